// Round 9
// baseline (801.016 us; speedup 1.0000x reference)
//
#include <hip/hip_runtime.h>

typedef __bf16 bf16;
typedef __bf16 bf16x8 __attribute__((ext_vector_type(8)));
typedef __bf16 bf16x4 __attribute__((ext_vector_type(4)));
typedef float  f32x4  __attribute__((ext_vector_type(4)));

#define LOG2E 1.4426950408889634f

// ---------------------------------------------------------------- helpers
__device__ __forceinline__ void gload_lds16(const void* g, void* l) {
    __builtin_amdgcn_global_load_lds(
        (__attribute__((address_space(1))) const void*)g,
        (__attribute__((address_space(3))) void*)l, 16, 0, 0);
}

// ---------------------------------------------------------------- f32 -> bf16 weight convert
__global__ __launch_bounds__(256) void cvt_bf16(const float* __restrict__ src,
                                                bf16* __restrict__ dst, int n) {
    int i = (blockIdx.x * 256 + threadIdx.x) * 4;
    if (i + 3 < n) {
        float4 v = *(const float4*)(src + i);
        bf16x4 o;
        o[0] = (bf16)v.x; o[1] = (bf16)v.y; o[2] = (bf16)v.z; o[3] = (bf16)v.w;
        *(bf16x4*)(dst + i) = o;
    }
}

// ---------------------------------------------------------------- LayerNorm (f32 in, bf16 out), row = 2048
__global__ __launch_bounds__(256) void ln_kernel(const float* __restrict__ x,
                                                 const float* __restrict__ wgt,
                                                 const float* __restrict__ bias,
                                                 bf16* __restrict__ out) {
    __shared__ float red[8];
    const int tid = threadIdx.x;
    const int lane = tid & 63, w = tid >> 6;
    const size_t row = blockIdx.x;
    const float4* xr = (const float4*)(x + row * 2048);
    float4 v0 = xr[tid];
    float4 v1 = xr[tid + 256];
    float s = v0.x + v0.y + v0.z + v0.w + v1.x + v1.y + v1.z + v1.w;
    float q = v0.x*v0.x + v0.y*v0.y + v0.z*v0.z + v0.w*v0.w
            + v1.x*v1.x + v1.y*v1.y + v1.z*v1.z + v1.w*v1.w;
    #pragma unroll
    for (int off = 32; off; off >>= 1) {
        s += __shfl_xor(s, off);
        q += __shfl_xor(q, off);
    }
    if (lane == 0) { red[w] = s; red[4 + w] = q; }
    __syncthreads();
    float S  = red[0] + red[1] + red[2] + red[3];
    float Q2 = red[4] + red[5] + red[6] + red[7];
    float mu = S * (1.0f / 2048.0f);
    float var = Q2 * (1.0f / 2048.0f) - mu * mu;
    float rstd = rsqrtf(var + 1e-5f);

    bf16* orow = out + row * 2048;
    int c0 = tid * 4;
    float vv[8] = {v0.x, v0.y, v0.z, v0.w, v1.x, v1.y, v1.z, v1.w};
    bf16x4 o;
    #pragma unroll
    for (int k = 0; k < 4; ++k)
        o[k] = (bf16)((vv[k] - mu) * rstd * wgt[c0 + k] + bias[c0 + k]);
    *(bf16x4*)(orow + c0) = o;
    #pragma unroll
    for (int k = 0; k < 4; ++k)
        o[k] = (bf16)((vv[4 + k] - mu) * rstd * wgt[1024 + c0 + k] + bias[1024 + c0 + k]);
    *(bf16x4*)(orow + 1024 + c0) = o;
}

// ---------------------------------------------------------------- GEMM  C[M,N] = A[M,K] * B[N,K]^T  (both bf16)
// 128x128 tile, 8 waves (4Mx2N), 512 threads, BK=32, FIVE LDS buffers (80KB ->
// exactly 2 blocks/CU). Prefetch DEPTH 4: stage tile t+4 while computing t;
// vmcnt(8) (= 2 loads/thr/stage x 4 in-flight stages) guarantees tile t landed,
// waited-on loads are 4 K-steps (~600cyc) old, x2 blocks interleaved.
// LDS layout: 8 x 1KB row-group blocks per operand; every fragment ds_read_b128
// is one contiguous 1KB per wave -> zero bank conflicts, no swizzle.
// Raw s_barrier only (never __syncthreads: it drains vmcnt(0)).
// EPI: 0 bf16 out | 1 +bias exact GELU bf16 | 2 res+acc f32 | 3 res+acc+bias f32
template <int EPI>
__global__ __launch_bounds__(512, 4) void gemmD(const bf16* __restrict__ A,
                                                const bf16* __restrict__ B,
                                                void* __restrict__ OutP,
                                                const float* __restrict__ bias,
                                                const float* __restrict__ res,
                                                int M, int N, int K) {
    extern __shared__ __align__(16) char lds[];   // 5 x (A 8KB | B 8KB) = 81920
    const int tid = threadIdx.x;
    const int lane = tid & 63;
    const int w = tid >> 6, wr = w >> 1, wc = w & 1;
    const int lo = lane & 15, hi = lane >> 4;

    // ---- block swizzle: XCD-bijective, then column-groups of 4 (M-major inside)
    const int nwg = gridDim.x;
    const int bid = blockIdx.x;
    const int q = nwg >> 3, r = nwg & 7, xcd = bid & 7, off = bid >> 3;
    const int s = (xcd < r ? xcd * (q + 1) : r * (q + 1) + (xcd - r) * q) + off;
    const int MB = M / 128;
    const int per = MB * 4;
    const int grp = s / per, t2 = s - grp * per;
    const int brow = (t2 % MB) * 128;
    const int bcol = (grp * 4 + t2 / MB) * 128;

    // ---- staging: thread tid covers row (tid>>6)*16 + ((tid>>2)&15), k-col (tid&3)*8.
    //      dest tid*16 reproduces block layout exactly; 4 lanes = 64B contiguous/row.
    const int srow = (tid >> 6) * 16 + ((tid >> 2) & 15);
    const int scol = (tid & 3) * 8;
    const bf16* Ag = A + (size_t)(brow + srow) * K + scol;
    const bf16* Bg = B + (size_t)(bcol + srow) * K + scol;
    char* d0 = lds + tid * 16;

    auto stage = [&](int bf, int kt) {
        char* d = d0 + bf * 16384;
        gload_lds16(Ag + kt * 32, d);
        gload_lds16(Bg + kt * 32, d + 8192);
    };

    f32x4 acc[2][4] = {};
    const int NT = K >> 5;
    // fragment offset within a 1KB block: row lo (64B rows), k-slot hi (16B)
    const int fo = (lo << 6) + (hi << 4);

    stage(0, 0); stage(1, 1); stage(2, 2); stage(3, 3);
    int bi = 0, sb = 4;                    // compute buffer, stage buffer
    for (int kt = 0; kt < NT; ++kt) {
        if (kt + 4 < NT) stage(sb, kt + 4);
        const int rem = NT - 1 - kt;       // tiles still in queue after this one
        if (rem >= 4)      asm volatile("s_waitcnt vmcnt(8)" ::: "memory");
        else if (rem == 3) asm volatile("s_waitcnt vmcnt(6)" ::: "memory");
        else if (rem == 2) asm volatile("s_waitcnt vmcnt(4)" ::: "memory");
        else if (rem == 1) asm volatile("s_waitcnt vmcnt(2)" ::: "memory");
        else               asm volatile("s_waitcnt vmcnt(0)" ::: "memory");
        __builtin_amdgcn_s_barrier();

        const char* ab = lds + bi * 16384;
        bf16x8 af[2], bv[4];
        #pragma unroll
        for (int m = 0; m < 2; ++m)
            af[m] = *(const bf16x8*)(ab + ((wr * 2 + m) << 10) + fo);
        #pragma unroll
        for (int n = 0; n < 4; ++n)
            bv[n] = *(const bf16x8*)(ab + 8192 + ((wc * 4 + n) << 10) + fo);
        #pragma unroll
        for (int m = 0; m < 2; ++m)
            #pragma unroll
            for (int n = 0; n < 4; ++n)
                acc[m][n] = __builtin_amdgcn_mfma_f32_16x16x32_bf16(af[m], bv[n], acc[m][n], 0, 0, 0);
        __builtin_amdgcn_s_barrier();

        bi = (bi == 4) ? 0 : bi + 1;
        sb = (sb == 4) ? 0 : sb + 1;
    }

    // ---- epilogue: row = brow + wr*32 + m*16 + hi*4 + rr ; col = bcol + wc*64 + n*16 + lo
    float* outF = (float*)OutP;
    bf16*  outB = (bf16*)OutP;
    #pragma unroll
    for (int n = 0; n < 4; ++n) {
        const int col = bcol + wc * 64 + n * 16 + lo;
        float bv2 = 0.f;
        if (EPI == 1 || EPI == 3) bv2 = bias[col];
        #pragma unroll
        for (int m = 0; m < 2; ++m) {
            #pragma unroll
            for (int rr = 0; rr < 4; ++rr) {
                const int row = brow + wr * 32 + m * 16 + hi * 4 + rr;
                float v = acc[m][n][rr];
                if (EPI == 0) {
                    outB[(size_t)row * N + col] = (bf16)v;
                } else if (EPI == 1) {
                    v += bv2;
                    v = 0.5f * v * (1.0f + erff(v * 0.70710678118654752f));
                    outB[(size_t)row * N + col] = (bf16)v;
                } else if (EPI == 2) {
                    outF[(size_t)row * N + col] = res[(size_t)row * N + col] + v;
                } else {
                    outF[(size_t)row * N + col] = res[(size_t)row * N + col] + v + bv2;
                }
            }
        }
    }
}

// ---------------------------------------------------------------- RoPE + GQA scatter
__global__ __launch_bounds__(256) void rope_scatter(const bf16* __restrict__ qkv,
                                                    const float* __restrict__ cosb,
                                                    const float* __restrict__ sinb,
                                                    bf16* __restrict__ Q,
                                                    bf16* __restrict__ Kg,
                                                    bf16* __restrict__ Vt) {
    const int tid = threadIdx.x;
    const int row = blockIdx.x;          // b*T + t
    const int b = row >> 11, t = row & 2047;
    const bf16* src = qkv + (size_t)row * 3072;
    for (int i = tid; i < 1536; i += 256) {
        int slot = i >> 6;               // 0..23  = g*6 + m
        int d = i & 63;
        int g = slot / 6, m = slot - g * 6;
        float v1 = (float)src[slot * 128 + d];
        float v2 = (float)src[slot * 128 + d + 64];
        float o1, o2;
        if (m < 5) {
            float c1 = cosb[t * 128 + d],      s1 = sinb[t * 128 + d];
            float c2 = cosb[t * 128 + d + 64], s2 = sinb[t * 128 + d + 64];
            o1 = v1 * c1 - v2 * s1;
            o2 = v2 * c2 + v1 * s2;
        } else {
            o1 = v1; o2 = v2;
        }
        if (m < 4) {
            int hh = g * 4 + m;
            size_t base = ((size_t)(b * 16 + hh) * 2048 + t) * 128;
            Q[base + d] = (bf16)o1;
            Q[base + d + 64] = (bf16)o2;
        } else if (m == 4) {
            size_t base = ((size_t)(b * 4 + g) * 2048 + t) * 128;
            Kg[base + d] = (bf16)o1;
            Kg[base + d + 64] = (bf16)o2;
        } else {
            size_t base = (size_t)(b * 4 + g) * 128;
            Vt[(base + d) * 2048 + t] = (bf16)o1;
            Vt[(base + d + 64) * 2048 + t] = (bf16)o2;
        }
    }
}

// ---------------------------------------------------------------- causal flash attention
// Balanced: block bx handles q-tiles {bx, 31-bx} -> every block does 33 KV-tile steps.
__global__ __launch_bounds__(256) void attn_kernel(const bf16* __restrict__ Q,
                                                   const bf16* __restrict__ Kg,
                                                   const bf16* __restrict__ Vt,
                                                   bf16* __restrict__ Y) {
    __shared__ __align__(16) bf16 Ks[64 * 128];
    __shared__ __align__(16) bf16 Vs[128 * 64];
    __shared__ __align__(16) bf16 Ps[4][16 * 80];

    const int tid = threadIdx.x;
    const int lane = tid & 63, w = tid >> 6;
    const int lo = lane & 15, hi = lane >> 4;
    const int bh = blockIdx.y;
    const int b = bh >> 4, h = bh & 15;
    const int g = h >> 2;

    const bf16* Kbase = Kg + (size_t)(b * 4 + g) * 2048 * 128;
    const bf16* Vbase = Vt + (size_t)(b * 4 + g) * 128 * 2048;
    const float scale = 0.08838834764831845f;
    bf16* pw = &Ps[w][0];

    #pragma unroll 1
    for (int pass = 0; pass < 2; ++pass) {
        const int qt = pass ? 31 - (int)blockIdx.x : (int)blockIdx.x;
        const int q0 = qt * 64;

        bf16x8 qf[4];
        {
            const size_t qbase = ((size_t)bh * 2048 + q0 + w * 16 + lo) * 128;
            #pragma unroll
            for (int dd = 0; dd < 4; ++dd)
                qf[dd] = *(const bf16x8*)(Q + qbase + dd * 32 + hi * 8);
        }

        float m_r[4], l_r[4];
        f32x4 oacc[8] = {};
        #pragma unroll
        for (int rr = 0; rr < 4; ++rr) { m_r[rr] = -1e30f; l_r[rr] = 0.f; }

        for (int kt = 0; kt <= qt; ++kt) {
            #pragma unroll
            for (int it = 0; it < 4; ++it) {
                int ob = (it * 256 + tid) * 16;
                int rk = ob >> 8, cb = ob & 255;
                bf16x8 kv = *(const bf16x8*)(Kbase + (size_t)(kt * 64 + rk) * 128 + (cb >> 1));
                *(bf16x8*)((char*)Ks + rk * 256 + (cb ^ ((rk & 7) << 4))) = kv;
                int dv = ob >> 7, cv = ob & 127;
                bf16x8 vv = *(const bf16x8*)(Vbase + (size_t)dv * 2048 + kt * 64 + (cv >> 1));
                *(bf16x8*)((char*)Vs + dv * 128 + (cv ^ ((dv & 7) << 4))) = vv;
            }
            __syncthreads();

            f32x4 sj[4];
            #pragma unroll
            for (int j = 0; j < 4; ++j) {
                f32x4 a = {};
                int rk = j * 16 + lo;
                #pragma unroll
                for (int dd = 0; dd < 4; ++dd) {
                    int cb = dd * 64 + hi * 16;
                    bf16x8 kf = *(const bf16x8*)((const char*)Ks + rk * 256 + (cb ^ ((rk & 7) << 4)));
                    a = __builtin_amdgcn_mfma_f32_16x16x32_bf16(qf[dd], kf, a, 0, 0, 0);
                }
                sj[j] = a;
            }

            float sv[4][4];
            const bool diag = (kt == qt);
            #pragma unroll
            for (int j = 0; j < 4; ++j)
                #pragma unroll
                for (int rr = 0; rr < 4; ++rr) {
                    float v = sj[j][rr] * scale;
                    if (diag) {
                        int tg = kt * 64 + j * 16 + lo;
                        int qg = q0 + w * 16 + hi * 4 + rr;
                        if (tg > qg) v = -1e30f;
                    }
                    sv[j][rr] = v;
                }

            float mx[4];
            #pragma unroll
            for (int rr = 0; rr < 4; ++rr) {
                float m0 = fmaxf(fmaxf(sv[0][rr], sv[1][rr]), fmaxf(sv[2][rr], sv[3][rr]));
                #pragma unroll
                for (int off = 8; off; off >>= 1) m0 = fmaxf(m0, __shfl_xor(m0, off, 16));
                mx[rr] = m0;
            }
            float p[4][4];
            float rs[4], al[4];
            #pragma unroll
            for (int rr = 0; rr < 4; ++rr) {
                float mnew = fmaxf(m_r[rr], mx[rr]);
                #pragma unroll
                for (int j = 0; j < 4; ++j)
                    p[j][rr] = exp2f((sv[j][rr] - mnew) * LOG2E);
                float s0 = p[0][rr] + p[1][rr] + p[2][rr] + p[3][rr];
                #pragma unroll
                for (int off = 8; off; off >>= 1) s0 += __shfl_xor(s0, off, 16);
                rs[rr] = s0;
                al[rr] = exp2f((m_r[rr] - mnew) * LOG2E);
                l_r[rr] = l_r[rr] * al[rr] + rs[rr];
                m_r[rr] = mnew;
            }
            #pragma unroll
            for (int dn = 0; dn < 8; ++dn)
                #pragma unroll
                for (int rr = 0; rr < 4; ++rr) oacc[dn][rr] *= al[rr];

            #pragma unroll
            for (int j = 0; j < 4; ++j)
                #pragma unroll
                for (int rr = 0; rr < 4; ++rr)
                    pw[(hi * 4 + rr) * 80 + j * 16 + lo] = (bf16)p[j][rr];

            #pragma unroll
            for (int tc = 0; tc < 2; ++tc) {
                bf16x8 pf = *(const bf16x8*)(pw + lo * 80 + tc * 32 + hi * 8);
                #pragma unroll
                for (int dn = 0; dn < 8; ++dn) {
                    int rv = dn * 16 + lo;
                    int cv = tc * 64 + hi * 16;
                    bf16x8 vf = *(const bf16x8*)((const char*)Vs + rv * 128 + (cv ^ ((rv & 7) << 4)));
                    oacc[dn] = __builtin_amdgcn_mfma_f32_16x16x32_bf16(pf, vf, oacc[dn], 0, 0, 0);
                }
            }
            __syncthreads();
        }

        #pragma unroll
        for (int dn = 0; dn < 8; ++dn)
            #pragma unroll
            for (int rr = 0; rr < 4; ++rr) {
                int qg = q0 + w * 16 + hi * 4 + rr;
                Y[((size_t)b * 2048 + qg) * 2048 + h * 128 + dn * 16 + lo] =
                    (bf16)(oacc[dn][rr] / l_r[rr]);
            }
    }
}

// ---------------------------------------------------------------- launch
extern "C" void kernel_launch(void* const* d_in, const int* in_sizes, int n_in,
                              void* d_out, int out_size, void* d_ws, size_t ws_size,
                              hipStream_t stream) {
    const float* x      = (const float*)d_in[0];
    const float* cosb   = (const float*)d_in[1];
    const float* sinb   = (const float*)d_in[2];
    const float* ln1_w  = (const float*)d_in[4];
    const float* ln1_b  = (const float*)d_in[5];
    const float* qkv_w  = (const float*)d_in[6];
    const float* proj_w = (const float*)d_in[7];
    const float* ln2_w  = (const float*)d_in[8];
    const float* ln2_b  = (const float*)d_in[9];
    const float* fc1_w  = (const float*)d_in[10];
    const float* fc1_b  = (const float*)d_in[11];
    const float* fc2_w  = (const float*)d_in[12];
    const float* fc2_b  = (const float*)d_in[13];
    float* out = (float*)d_out;

    char* ws = (char*)d_ws;
    bf16*  w_qkv  = (bf16*)(ws + 0ull);            // 3072x2048
    bf16*  w_proj = (bf16*)(ws + 12582912ull);     // 2048x2048
    bf16*  w_fc1  = (bf16*)(ws + 20971520ull);     // 8192x2048
    bf16*  w_fc2  = (bf16*)(ws + 54525952ull);     // 2048x8192
    float* x2     = (float*)(ws + 88080384ull);    // 4096x2048 f32
    bf16*  lnout  = (bf16*)(ws + 121634816ull);    // 4096x2048
    char*  R      = ws + 138412032ull;             // aliased region (67.1 MB)
    bf16*  qkvo = (bf16*)(R);                      // 4096x3072
    bf16*  Qb   = (bf16*)(R + 25165824ull);        // 2,16,2048,128
    bf16*  Kb   = (bf16*)(R + 41943040ull);        // 2,4,2048,128
    bf16*  Vtb  = (bf16*)(R + 46137344ull);        // 2,4,128,2048
    bf16*  Yb   = (bf16*)(R + 50331648ull);        // 4096x2048
    bf16*  mlp  = (bf16*)(R);                      // 4096x8192 (aliases all above)

    constexpr int LDSD = 5 * 16384;                // 81920 B -> 2 blocks/CU

    cvt_bf16<<<6144,  256, 0, stream>>>(qkv_w,  w_qkv,  3072 * 2048);
    cvt_bf16<<<4096,  256, 0, stream>>>(proj_w, w_proj, 2048 * 2048);
    cvt_bf16<<<16384, 256, 0, stream>>>(fc1_w,  w_fc1,  8192 * 2048);
    cvt_bf16<<<16384, 256, 0, stream>>>(fc2_w,  w_fc2,  2048 * 8192);

    ln_kernel<<<4096, 256, 0, stream>>>(x, ln1_w, ln1_b, lnout);

    gemmD<0><<<768, 512, LDSD, stream>>>(lnout, w_qkv, qkvo, nullptr, nullptr,
                                         4096, 3072, 2048);

    rope_scatter<<<4096, 256, 0, stream>>>(qkvo, cosb, sinb, Qb, Kb, Vtb);

    attn_kernel<<<dim3(16, 32), 256, 0, stream>>>(Qb, Kb, Vtb, Yb);

    gemmD<2><<<512, 512, LDSD, stream>>>(Yb, w_proj, x2, nullptr, x,
                                         4096, 2048, 2048);

    ln_kernel<<<4096, 256, 0, stream>>>(x2, ln2_w, ln2_b, lnout);

    gemmD<1><<<2048, 512, LDSD, stream>>>(lnout, w_fc1, mlp, fc1_b, nullptr,
                                          4096, 8192, 2048);

    gemmD<3><<<512, 512, LDSD, stream>>>(mlp, w_fc2, out, fc2_b, x2,
                                         4096, 2048, 8192);
}

// Round 10
// 793.299 us; speedup vs baseline: 1.0097x; 1.0097x over previous
//
#include <hip/hip_runtime.h>

typedef __bf16 bf16;
typedef __bf16 bf16x8 __attribute__((ext_vector_type(8)));
typedef __bf16 bf16x4 __attribute__((ext_vector_type(4)));
typedef float  f32x4  __attribute__((ext_vector_type(4)));

#define LOG2E 1.4426950408889634f

// ---------------------------------------------------------------- helpers
__device__ __forceinline__ void gload_lds16(const void* g, void* l) {
    __builtin_amdgcn_global_load_lds(
        (__attribute__((address_space(1))) const void*)g,
        (__attribute__((address_space(3))) void*)l, 16, 0, 0);
}

// ---------------------------------------------------------------- f32 -> bf16 weight convert
__global__ __launch_bounds__(256) void cvt_bf16(const float* __restrict__ src,
                                                bf16* __restrict__ dst, int n) {
    int i = (blockIdx.x * 256 + threadIdx.x) * 4;
    if (i + 3 < n) {
        float4 v = *(const float4*)(src + i);
        bf16x4 o;
        o[0] = (bf16)v.x; o[1] = (bf16)v.y; o[2] = (bf16)v.z; o[3] = (bf16)v.w;
        *(bf16x4*)(dst + i) = o;
    }
}

// ---------------------------------------------------------------- out += p  (split-K combine)
__global__ __launch_bounds__(256) void add_f32(float* __restrict__ out,
                                               const float* __restrict__ p, int n) {
    int i = (blockIdx.x * 256 + threadIdx.x) * 4;
    if (i + 3 < n) {
        float4 a = *(const float4*)(out + i);
        float4 b = *(const float4*)(p + i);
        a.x += b.x; a.y += b.y; a.z += b.z; a.w += b.w;
        *(float4*)(out + i) = a;
    }
}

// ---------------------------------------------------------------- LayerNorm (f32 in, bf16 out), row = 2048
__global__ __launch_bounds__(256) void ln_kernel(const float* __restrict__ x,
                                                 const float* __restrict__ wgt,
                                                 const float* __restrict__ bias,
                                                 bf16* __restrict__ out) {
    __shared__ float red[8];
    const int tid = threadIdx.x;
    const int lane = tid & 63, w = tid >> 6;
    const size_t row = blockIdx.x;
    const float4* xr = (const float4*)(x + row * 2048);
    float4 v0 = xr[tid];
    float4 v1 = xr[tid + 256];
    float s = v0.x + v0.y + v0.z + v0.w + v1.x + v1.y + v1.z + v1.w;
    float q = v0.x*v0.x + v0.y*v0.y + v0.z*v0.z + v0.w*v0.w
            + v1.x*v1.x + v1.y*v1.y + v1.z*v1.z + v1.w*v1.w;
    #pragma unroll
    for (int off = 32; off; off >>= 1) {
        s += __shfl_xor(s, off);
        q += __shfl_xor(q, off);
    }
    if (lane == 0) { red[w] = s; red[4 + w] = q; }
    __syncthreads();
    float S  = red[0] + red[1] + red[2] + red[3];
    float Q2 = red[4] + red[5] + red[6] + red[7];
    float mu = S * (1.0f / 2048.0f);
    float var = Q2 * (1.0f / 2048.0f) - mu * mu;
    float rstd = rsqrtf(var + 1e-5f);

    bf16* orow = out + row * 2048;
    int c0 = tid * 4;
    float vv[8] = {v0.x, v0.y, v0.z, v0.w, v1.x, v1.y, v1.z, v1.w};
    bf16x4 o;
    #pragma unroll
    for (int k = 0; k < 4; ++k)
        o[k] = (bf16)((vv[k] - mu) * rstd * wgt[c0 + k] + bias[c0 + k]);
    *(bf16x4*)(orow + c0) = o;
    #pragma unroll
    for (int k = 0; k < 4; ++k)
        o[k] = (bf16)((vv[4 + k] - mu) * rstd * wgt[1024 + c0 + k] + bias[1024 + c0 + k]);
    *(bf16x4*)(orow + 1024 + c0) = o;
}

// ---------------------------------------------------------------- GEMM  C[M,N] = A[M,K]*B[N,K]^T (bf16)
// 256x256 tile, 8 waves (2Mx4N), 512 threads, per-wave 128x64 output (acc=128 VGPR:
// FLOP/LDS-byte = 43 vs 21 for 32x64 -> LDS and MFMA pipes balanced 1:1).
// BK=32, double-buffered 2x32KB LDS, counted vmcnt(4), raw s_barrier.
// LDS rows 64B, 4x16B slots XOR'd by row&3: fragment reads <=2-way (free);
// staging: 4 lanes = one 64B segment (coalesced), source-unit XOR matches read XOR.
// EPI: 0 bf16 | 1 +bias GELU bf16 | 3 res+acc+bias f32 |
//      4 splitK res+acc (y0) / raw acc->Aux (y1) | 5 = 4 with +bias on y0
template <int EPI>
__global__ __launch_bounds__(512, 2) void gemmE(const bf16* __restrict__ A,
                                                const bf16* __restrict__ B,
                                                void* __restrict__ OutP,
                                                const float* __restrict__ bias,
                                                const float* __restrict__ res,
                                                float* __restrict__ Aux,
                                                int M, int N, int Kc, int ldk) {
    extern __shared__ __align__(16) char lds[];   // 2 x (A 16KB | B 16KB)
    const int tid = threadIdx.x;
    const int lane = tid & 63;
    const int w = tid >> 6, wr = w >> 2, wc = w & 3;
    const int lo = lane & 15, hi = lane >> 4;
    const int koff = (EPI >= 4) ? (int)blockIdx.y * Kc : 0;

    // ---- block swizzle: XCD-bijective, then column-groups of 4 (M-major inside)
    const int nwg = gridDim.x;
    const int bid = blockIdx.x;
    const int q = nwg >> 3, r = nwg & 7, xcd = bid & 7, off = bid >> 3;
    const int s = (xcd < r ? xcd * (q + 1) : r * (q + 1) + (xcd - r) * q) + off;
    const int MB = M / 256;
    const int per = MB * 4;
    const int grp = s / per, t2 = s - grp * per;
    const int brow = (t2 % MB) * 256;
    const int bcol = (grp * 4 + t2 / MB) * 256;

    // ---- staging: thread t -> rows (t>>2), (t>>2)+128 ; 16B-unit (t&3)^((t>>2)&3)
    //      dest linear t*16 => LDS slot s of row r holds global unit s^(r&3)
    const int srow = tid >> 2;
    const int scol = ((tid & 3) ^ ((tid >> 2) & 3)) * 8;
    const bf16* Ag = A + (size_t)(brow + srow) * ldk + koff + scol;
    const bf16* Bg = B + (size_t)(bcol + srow) * ldk + koff + scol;
    const size_t R128 = (size_t)128 * ldk;
    char* d0 = lds + tid * 16;

    auto stage = [&](int bf, int kt) {
        char* d = d0 + bf * 32768;
        gload_lds16(Ag + kt * 32, d);
        gload_lds16(Ag + R128 + kt * 32, d + 8192);
        gload_lds16(Bg + kt * 32, d + 16384);
        gload_lds16(Bg + R128 + kt * 32, d + 24576);
    };

    f32x4 acc[8][4] = {};
    const int NT = Kc >> 5;
    const int xsl = (hi ^ (lo & 3)) << 4;   // slot holding k-unit hi for this lane's row

    stage(0, 0);
    #pragma unroll 1
    for (int kt = 0; kt < NT; ++kt) {
        const int cur = kt & 1;
        if (kt + 1 < NT) {
            stage(cur ^ 1, kt + 1);
            asm volatile("s_waitcnt vmcnt(4)" ::: "memory");
        } else {
            asm volatile("s_waitcnt vmcnt(0)" ::: "memory");
        }
        __builtin_amdgcn_s_barrier();

        const char* ab = lds + cur * 32768;
        const char* bb = ab + 16384;
        bf16x8 af[8], bv[4];
        #pragma unroll
        for (int m = 0; m < 4; ++m)
            af[m] = *(const bf16x8*)(ab + (wr * 128 + m * 16 + lo) * 64 + xsl);
        #pragma unroll
        for (int n = 0; n < 4; ++n)
            bv[n] = *(const bf16x8*)(bb + (wc * 64 + n * 16 + lo) * 64 + xsl);
        __builtin_amdgcn_s_setprio(1);
        #pragma unroll
        for (int m = 0; m < 4; ++m)
            #pragma unroll
            for (int n = 0; n < 4; ++n)
                acc[m][n] = __builtin_amdgcn_mfma_f32_16x16x32_bf16(af[m], bv[n], acc[m][n], 0, 0, 0);
        __builtin_amdgcn_s_setprio(0);
        #pragma unroll
        for (int m = 4; m < 8; ++m)
            af[m] = *(const bf16x8*)(ab + (wr * 128 + m * 16 + lo) * 64 + xsl);
        __builtin_amdgcn_s_setprio(1);
        #pragma unroll
        for (int m = 4; m < 8; ++m)
            #pragma unroll
            for (int n = 0; n < 4; ++n)
                acc[m][n] = __builtin_amdgcn_mfma_f32_16x16x32_bf16(af[m], bv[n], acc[m][n], 0, 0, 0);
        __builtin_amdgcn_s_setprio(0);
        __builtin_amdgcn_s_barrier();
    }

    // ---- epilogue: row = brow + wr*128 + m*16 + hi*4 + rr ; col = bcol + wc*64 + n*16 + lo
    float* outF = (float*)OutP;
    bf16*  outB = (bf16*)OutP;
    #pragma unroll
    for (int n = 0; n < 4; ++n) {
        const int col = bcol + wc * 64 + n * 16 + lo;
        float bv2 = 0.f;
        if (EPI == 1 || EPI == 3 || EPI == 5) bv2 = bias[col];
        #pragma unroll
        for (int m = 0; m < 8; ++m) {
            #pragma unroll
            for (int rr = 0; rr < 4; ++rr) {
                const int row = brow + wr * 128 + m * 16 + hi * 4 + rr;
                float v = acc[m][n][rr];
                if (EPI == 0) {
                    outB[(size_t)row * N + col] = (bf16)v;
                } else if (EPI == 1) {
                    v += bv2;
                    v = 0.5f * v * (1.0f + erff(v * 0.70710678118654752f));
                    outB[(size_t)row * N + col] = (bf16)v;
                } else if (EPI == 3) {
                    outF[(size_t)row * N + col] = res[(size_t)row * N + col] + v + bv2;
                } else if (EPI == 4 || EPI == 5) {
                    if (blockIdx.y == 0)
                        outF[(size_t)row * N + col] = res[(size_t)row * N + col] + v + bv2;
                    else
                        Aux[(size_t)row * N + col] = v;
                }
            }
        }
    }
}

// ---------------------------------------------------------------- RoPE + GQA scatter
__global__ __launch_bounds__(256) void rope_scatter(const bf16* __restrict__ qkv,
                                                    const float* __restrict__ cosb,
                                                    const float* __restrict__ sinb,
                                                    bf16* __restrict__ Q,
                                                    bf16* __restrict__ Kg,
                                                    bf16* __restrict__ Vt) {
    const int tid = threadIdx.x;
    const int row = blockIdx.x;          // b*T + t
    const int b = row >> 11, t = row & 2047;
    const bf16* src = qkv + (size_t)row * 3072;
    for (int i = tid; i < 1536; i += 256) {
        int slot = i >> 6;               // 0..23  = g*6 + m
        int d = i & 63;
        int g = slot / 6, m = slot - g * 6;
        float v1 = (float)src[slot * 128 + d];
        float v2 = (float)src[slot * 128 + d + 64];
        float o1, o2;
        if (m < 5) {
            float c1 = cosb[t * 128 + d],      s1 = sinb[t * 128 + d];
            float c2 = cosb[t * 128 + d + 64], s2 = sinb[t * 128 + d + 64];
            o1 = v1 * c1 - v2 * s1;
            o2 = v2 * c2 + v1 * s2;
        } else {
            o1 = v1; o2 = v2;
        }
        if (m < 4) {
            int hh = g * 4 + m;
            size_t base = ((size_t)(b * 16 + hh) * 2048 + t) * 128;
            Q[base + d] = (bf16)o1;
            Q[base + d + 64] = (bf16)o2;
        } else if (m == 4) {
            size_t base = ((size_t)(b * 4 + g) * 2048 + t) * 128;
            Kg[base + d] = (bf16)o1;
            Kg[base + d + 64] = (bf16)o2;
        } else {
            size_t base = (size_t)(b * 4 + g) * 128;
            Vt[(base + d) * 2048 + t] = (bf16)o1;
            Vt[(base + d + 64) * 2048 + t] = (bf16)o2;
        }
    }
}

// ---------------------------------------------------------------- causal flash attention
// Balanced: block bx handles q-tiles {bx, 31-bx} -> every block does 33 KV-tile steps.
__global__ __launch_bounds__(256) void attn_kernel(const bf16* __restrict__ Q,
                                                   const bf16* __restrict__ Kg,
                                                   const bf16* __restrict__ Vt,
                                                   bf16* __restrict__ Y) {
    __shared__ __align__(16) bf16 Ks[64 * 128];
    __shared__ __align__(16) bf16 Vs[128 * 64];
    __shared__ __align__(16) bf16 Ps[4][16 * 80];

    const int tid = threadIdx.x;
    const int lane = tid & 63, w = tid >> 6;
    const int lo = lane & 15, hi = lane >> 4;
    const int bh = blockIdx.y;
    const int b = bh >> 4, h = bh & 15;
    const int g = h >> 2;

    const bf16* Kbase = Kg + (size_t)(b * 4 + g) * 2048 * 128;
    const bf16* Vbase = Vt + (size_t)(b * 4 + g) * 128 * 2048;
    const float scale = 0.08838834764831845f;
    bf16* pw = &Ps[w][0];

    #pragma unroll 1
    for (int pass = 0; pass < 2; ++pass) {
        const int qt = pass ? 31 - (int)blockIdx.x : (int)blockIdx.x;
        const int q0 = qt * 64;

        bf16x8 qf[4];
        {
            const size_t qbase = ((size_t)bh * 2048 + q0 + w * 16 + lo) * 128;
            #pragma unroll
            for (int dd = 0; dd < 4; ++dd)
                qf[dd] = *(const bf16x8*)(Q + qbase + dd * 32 + hi * 8);
        }

        float m_r[4], l_r[4];
        f32x4 oacc[8] = {};
        #pragma unroll
        for (int rr = 0; rr < 4; ++rr) { m_r[rr] = -1e30f; l_r[rr] = 0.f; }

        for (int kt = 0; kt <= qt; ++kt) {
            #pragma unroll
            for (int it = 0; it < 4; ++it) {
                int ob = (it * 256 + tid) * 16;
                int rk = ob >> 8, cb = ob & 255;
                bf16x8 kv = *(const bf16x8*)(Kbase + (size_t)(kt * 64 + rk) * 128 + (cb >> 1));
                *(bf16x8*)((char*)Ks + rk * 256 + (cb ^ ((rk & 7) << 4))) = kv;
                int dv = ob >> 7, cv = ob & 127;
                bf16x8 vv = *(const bf16x8*)(Vbase + (size_t)dv * 2048 + kt * 64 + (cv >> 1));
                *(bf16x8*)((char*)Vs + dv * 128 + (cv ^ ((dv & 7) << 4))) = vv;
            }
            __syncthreads();

            f32x4 sj[4];
            #pragma unroll
            for (int j = 0; j < 4; ++j) {
                f32x4 a = {};
                int rk = j * 16 + lo;
                #pragma unroll
                for (int dd = 0; dd < 4; ++dd) {
                    int cb = dd * 64 + hi * 16;
                    bf16x8 kf = *(const bf16x8*)((const char*)Ks + rk * 256 + (cb ^ ((rk & 7) << 4)));
                    a = __builtin_amdgcn_mfma_f32_16x16x32_bf16(qf[dd], kf, a, 0, 0, 0);
                }
                sj[j] = a;
            }

            float sv[4][4];
            const bool diag = (kt == qt);
            #pragma unroll
            for (int j = 0; j < 4; ++j)
                #pragma unroll
                for (int rr = 0; rr < 4; ++rr) {
                    float v = sj[j][rr] * scale;
                    if (diag) {
                        int tg = kt * 64 + j * 16 + lo;
                        int qg = q0 + w * 16 + hi * 4 + rr;
                        if (tg > qg) v = -1e30f;
                    }
                    sv[j][rr] = v;
                }

            float mx[4];
            #pragma unroll
            for (int rr = 0; rr < 4; ++rr) {
                float m0 = fmaxf(fmaxf(sv[0][rr], sv[1][rr]), fmaxf(sv[2][rr], sv[3][rr]));
                #pragma unroll
                for (int off = 8; off; off >>= 1) m0 = fmaxf(m0, __shfl_xor(m0, off, 16));
                mx[rr] = m0;
            }
            float p[4][4];
            float rs[4], al[4];
            #pragma unroll
            for (int rr = 0; rr < 4; ++rr) {
                float mnew = fmaxf(m_r[rr], mx[rr]);
                #pragma unroll
                for (int j = 0; j < 4; ++j)
                    p[j][rr] = exp2f((sv[j][rr] - mnew) * LOG2E);
                float s0 = p[0][rr] + p[1][rr] + p[2][rr] + p[3][rr];
                #pragma unroll
                for (int off = 8; off; off >>= 1) s0 += __shfl_xor(s0, off, 16);
                rs[rr] = s0;
                al[rr] = exp2f((m_r[rr] - mnew) * LOG2E);
                l_r[rr] = l_r[rr] * al[rr] + rs[rr];
                m_r[rr] = mnew;
            }
            #pragma unroll
            for (int dn = 0; dn < 8; ++dn)
                #pragma unroll
                for (int rr = 0; rr < 4; ++rr) oacc[dn][rr] *= al[rr];

            #pragma unroll
            for (int j = 0; j < 4; ++j)
                #pragma unroll
                for (int rr = 0; rr < 4; ++rr)
                    pw[(hi * 4 + rr) * 80 + j * 16 + lo] = (bf16)p[j][rr];

            #pragma unroll
            for (int tc = 0; tc < 2; ++tc) {
                bf16x8 pf = *(const bf16x8*)(pw + lo * 80 + tc * 32 + hi * 8);
                #pragma unroll
                for (int dn = 0; dn < 8; ++dn) {
                    int rv = dn * 16 + lo;
                    int cv = tc * 64 + hi * 16;
                    bf16x8 vf = *(const bf16x8*)((const char*)Vs + rv * 128 + (cv ^ ((rv & 7) << 4)));
                    oacc[dn] = __builtin_amdgcn_mfma_f32_16x16x32_bf16(pf, vf, oacc[dn], 0, 0, 0);
                }
            }
            __syncthreads();
        }

        #pragma unroll
        for (int dn = 0; dn < 8; ++dn)
            #pragma unroll
            for (int rr = 0; rr < 4; ++rr) {
                int qg = q0 + w * 16 + hi * 4 + rr;
                Y[((size_t)b * 2048 + qg) * 2048 + h * 128 + dn * 16 + lo] =
                    (bf16)(oacc[dn][rr] / l_r[rr]);
            }
    }
}

// ---------------------------------------------------------------- launch
extern "C" void kernel_launch(void* const* d_in, const int* in_sizes, int n_in,
                              void* d_out, int out_size, void* d_ws, size_t ws_size,
                              hipStream_t stream) {
    const float* x      = (const float*)d_in[0];
    const float* cosb   = (const float*)d_in[1];
    const float* sinb   = (const float*)d_in[2];
    const float* ln1_w  = (const float*)d_in[4];
    const float* ln1_b  = (const float*)d_in[5];
    const float* qkv_w  = (const float*)d_in[6];
    const float* proj_w = (const float*)d_in[7];
    const float* ln2_w  = (const float*)d_in[8];
    const float* ln2_b  = (const float*)d_in[9];
    const float* fc1_w  = (const float*)d_in[10];
    const float* fc1_b  = (const float*)d_in[11];
    const float* fc2_w  = (const float*)d_in[12];
    const float* fc2_b  = (const float*)d_in[13];
    float* out = (float*)d_out;

    char* ws = (char*)d_ws;
    bf16*  w_qkv  = (bf16*)(ws + 0ull);            // 3072x2048
    bf16*  w_proj = (bf16*)(ws + 12582912ull);     // 2048x2048
    bf16*  w_fc1  = (bf16*)(ws + 20971520ull);     // 8192x2048 (dead after fc1)
    bf16*  w_fc2  = (bf16*)(ws + 54525952ull);     // 2048x8192
    float* x2     = (float*)(ws + 88080384ull);    // 4096x2048 f32
    bf16*  lnout  = (bf16*)(ws + 121634816ull);    // 4096x2048
    char*  R      = ws + 138412032ull;             // aliased region (67.1 MB)
    bf16*  qkvo = (bf16*)(R);                      // 4096x3072
    bf16*  Qb   = (bf16*)(R + 25165824ull);        // 2,16,2048,128
    bf16*  Kb   = (bf16*)(R + 41943040ull);        // 2,4,2048,128
    bf16*  Vtb  = (bf16*)(R + 46137344ull);        // 2,4,128,2048
    bf16*  Yb   = (bf16*)(R + 50331648ull);        // 4096x2048
    bf16*  mlp  = (bf16*)(R);                      // 4096x8192 (aliases all above)
    float* p_proj = (float*)(R);                   // proj splitK partial (qkvo/Qb region, dead then)
    float* p_fc2  = (float*)(ws + 20971520ull);    // fc2 splitK partial (w_fc1 region, dead then)

    constexpr int LDSE = 65536;

    cvt_bf16<<<6144,  256, 0, stream>>>(qkv_w,  w_qkv,  3072 * 2048);
    cvt_bf16<<<4096,  256, 0, stream>>>(proj_w, w_proj, 2048 * 2048);
    cvt_bf16<<<16384, 256, 0, stream>>>(fc1_w,  w_fc1,  8192 * 2048);
    cvt_bf16<<<16384, 256, 0, stream>>>(fc2_w,  w_fc2,  2048 * 8192);

    ln_kernel<<<4096, 256, 0, stream>>>(x, ln1_w, ln1_b, lnout);

    gemmE<0><<<dim3(192, 1), 512, LDSE, stream>>>(lnout, w_qkv, qkvo, nullptr, nullptr,
                                                  nullptr, 4096, 3072, 2048, 2048);

    rope_scatter<<<4096, 256, 0, stream>>>(qkvo, cosb, sinb, Qb, Kb, Vtb);

    attn_kernel<<<dim3(16, 32), 256, 0, stream>>>(Qb, Kb, Vtb, Yb);

    // proj split-K=2: y0 -> x2 = x + acc0 ; y1 -> p_proj = acc1 ; x2 += p_proj
    gemmE<4><<<dim3(128, 2), 512, LDSE, stream>>>(Yb, w_proj, x2, nullptr, x,
                                                  p_proj, 4096, 2048, 1024, 2048);
    add_f32<<<8192, 256, 0, stream>>>(x2, p_proj, 4096 * 2048);

    ln_kernel<<<4096, 256, 0, stream>>>(x2, ln2_w, ln2_b, lnout);

    gemmE<1><<<dim3(512, 1), 512, LDSE, stream>>>(lnout, w_fc1, mlp, fc1_b, nullptr,
                                                  nullptr, 4096, 8192, 2048, 2048);

    // fc2 split-K=2: y0 -> out = x2 + acc0 + bias ; y1 -> p_fc2 = acc1 ; out += p_fc2
    gemmE<5><<<dim3(128, 2), 512, LDSE, stream>>>(mlp, w_fc2, out, fc2_b, x2,
                                                  p_fc2, 4096, 2048, 4096, 8192);
    add_f32<<<8192, 256, 0, stream>>>(out, p_fc2, 4096 * 2048);
}

// Round 11
// 706.580 us; speedup vs baseline: 1.1337x; 1.1227x over previous
//
#include <hip/hip_runtime.h>

typedef __bf16 bf16;
typedef __bf16 bf16x8 __attribute__((ext_vector_type(8)));
typedef __bf16 bf16x4 __attribute__((ext_vector_type(4)));
typedef float  f32x4  __attribute__((ext_vector_type(4)));

#define LOG2E 1.4426950408889634f

// ---------------------------------------------------------------- helpers
__device__ __forceinline__ void gload_lds16(const void* g, void* l) {
    __builtin_amdgcn_global_load_lds(
        (__attribute__((address_space(1))) const void*)g,
        (__attribute__((address_space(3))) void*)l, 16, 0, 0);
}

// ---------------------------------------------------------------- f32 -> bf16 weight convert
__global__ __launch_bounds__(256) void cvt_bf16(const float* __restrict__ src,
                                                bf16* __restrict__ dst, int n) {
    int i = (blockIdx.x * 256 + threadIdx.x) * 4;
    if (i + 3 < n) {
        float4 v = *(const float4*)(src + i);
        bf16x4 o;
        o[0] = (bf16)v.x; o[1] = (bf16)v.y; o[2] = (bf16)v.z; o[3] = (bf16)v.w;
        *(bf16x4*)(dst + i) = o;
    }
}

// ---------------------------------------------------------------- LayerNorm (f32 in, bf16 out), row = 2048
__global__ __launch_bounds__(256) void ln_kernel(const float* __restrict__ x,
                                                 const float* __restrict__ wgt,
                                                 const float* __restrict__ bias,
                                                 bf16* __restrict__ out) {
    __shared__ float red[8];
    const int tid = threadIdx.x;
    const int lane = tid & 63, w = tid >> 6;
    const size_t row = blockIdx.x;
    const float4* xr = (const float4*)(x + row * 2048);
    float4 v0 = xr[tid];
    float4 v1 = xr[tid + 256];
    float s = v0.x + v0.y + v0.z + v0.w + v1.x + v1.y + v1.z + v1.w;
    float q = v0.x*v0.x + v0.y*v0.y + v0.z*v0.z + v0.w*v0.w
            + v1.x*v1.x + v1.y*v1.y + v1.z*v1.z + v1.w*v1.w;
    #pragma unroll
    for (int off = 32; off; off >>= 1) {
        s += __shfl_xor(s, off);
        q += __shfl_xor(q, off);
    }
    if (lane == 0) { red[w] = s; red[4 + w] = q; }
    __syncthreads();
    float S  = red[0] + red[1] + red[2] + red[3];
    float Q2 = red[4] + red[5] + red[6] + red[7];
    float mu = S * (1.0f / 2048.0f);
    float var = Q2 * (1.0f / 2048.0f) - mu * mu;
    float rstd = rsqrtf(var + 1e-5f);

    bf16* orow = out + row * 2048;
    int c0 = tid * 4;
    float vv[8] = {v0.x, v0.y, v0.z, v0.w, v1.x, v1.y, v1.z, v1.w};
    bf16x4 o;
    #pragma unroll
    for (int k = 0; k < 4; ++k)
        o[k] = (bf16)((vv[k] - mu) * rstd * wgt[c0 + k] + bias[c0 + k]);
    *(bf16x4*)(orow + c0) = o;
    #pragma unroll
    for (int k = 0; k < 4; ++k)
        o[k] = (bf16)((vv[4 + k] - mu) * rstd * wgt[1024 + c0 + k] + bias[1024 + c0 + k]);
    *(bf16x4*)(orow + 1024 + c0) = o;
}

// ---------------------------------------------------------------- 128x128 GEMM (R6 gemmB, session-best; conflicts measured 0)
// 8 waves (4x2), 512 threads, BK=64, dbuf 2x32KB, vmcnt(4), XOR unit-swizzle.
// EPI: 0 bf16 | 1 +bias GELU bf16 | 2 res+acc f32 | 3 res+acc+bias f32
template <int EPI>
__global__ __launch_bounds__(512, 4) void gemmB(const bf16* __restrict__ A,
                                                const bf16* __restrict__ B,
                                                void* __restrict__ OutP,
                                                const float* __restrict__ bias,
                                                const float* __restrict__ res,
                                                int M, int N, int K) {
    __shared__ __align__(16) char lds[65536];
    const int tid = threadIdx.x;
    const int lane = tid & 63;
    const int w = tid >> 6, wr = w >> 1, wc = w & 1;
    const int lo = lane & 15, hi = lane >> 4;

    const int nwg = gridDim.x;
    const int bid = blockIdx.x;
    const int q = nwg >> 3, r = nwg & 7, xcd = bid & 7, off = bid >> 3;
    const int s = (xcd < r ? xcd * (q + 1) : r * (q + 1) + (xcd - r) * q) + off;
    const int MB = M / 128;
    const int per = MB * 4;
    const int grp = s / per, t2 = s - grp * per;
    const int brow = (t2 % MB) * 128;
    const int bcol = (grp * 4 + t2 / MB) * 128;

    const int sr = tid >> 3;
    const int su = (tid & 7) ^ (sr & 7);
    const bf16* Ag = A + (size_t)(brow + sr) * K + su * 8;
    const bf16* Bg = B + (size_t)(bcol + sr) * K + su * 8;
    const size_t K64 = (size_t)64 * K;
    char* dst0 = lds + tid * 16;

    auto stage = [&](int bf, int kt) {
        char* d = dst0 + bf * 32768;
        gload_lds16(Ag + kt * 64, d);
        gload_lds16(Ag + K64 + kt * 64, d + 8192);
        gload_lds16(Bg + kt * 64, d + 16384);
        gload_lds16(Bg + K64 + kt * 64, d + 24576);
    };

    f32x4 acc[2][4] = {};
    const int NT = K >> 6;

    stage(0, 0);
    for (int kt = 0; kt < NT; ++kt) {
        const int cur = kt & 1;
        if (kt + 1 < NT) {
            stage(cur ^ 1, kt + 1);
            asm volatile("s_waitcnt vmcnt(4)" ::: "memory");
        } else {
            asm volatile("s_waitcnt vmcnt(0)" ::: "memory");
        }
        __builtin_amdgcn_s_barrier();

        const char* ab = lds + cur * 32768;
        const char* bb = ab + 16384;
        bf16x8 af[2][2], bfv[4][2];
        #pragma unroll
        for (int m = 0; m < 2; ++m) {
            const int rA = wr * 32 + m * 16 + lo;
            #pragma unroll
            for (int ks = 0; ks < 2; ++ks)
                af[m][ks] = *(const bf16x8*)(ab + rA * 128 + (((ks * 4 + hi) ^ (lo & 7)) << 4));
        }
        #pragma unroll
        for (int n = 0; n < 4; ++n) {
            const int rB = wc * 64 + n * 16 + lo;
            #pragma unroll
            for (int ks = 0; ks < 2; ++ks)
                bfv[n][ks] = *(const bf16x8*)(bb + rB * 128 + (((ks * 4 + hi) ^ (lo & 7)) << 4));
        }
        __builtin_amdgcn_s_setprio(1);
        #pragma unroll
        for (int m = 0; m < 2; ++m)
            #pragma unroll
            for (int n = 0; n < 4; ++n)
                #pragma unroll
                for (int ks = 0; ks < 2; ++ks)
                    acc[m][n] = __builtin_amdgcn_mfma_f32_16x16x32_bf16(af[m][ks], bfv[n][ks], acc[m][n], 0, 0, 0);
        __builtin_amdgcn_s_setprio(0);
        __builtin_amdgcn_s_barrier();
    }

    float* outF = (float*)OutP;
    bf16*  outB = (bf16*)OutP;
    #pragma unroll
    for (int n = 0; n < 4; ++n) {
        const int col = bcol + wc * 64 + n * 16 + lo;
        float bv = 0.f;
        if (EPI == 1 || EPI == 3) bv = bias[col];
        #pragma unroll
        for (int m = 0; m < 2; ++m) {
            #pragma unroll
            for (int rr = 0; rr < 4; ++rr) {
                const int row = brow + wr * 32 + m * 16 + hi * 4 + rr;
                float v = acc[m][n][rr];
                if (EPI == 0) {
                    outB[(size_t)row * N + col] = (bf16)v;
                } else if (EPI == 1) {
                    v += bv;
                    v = 0.5f * v * (1.0f + erff(v * 0.70710678118654752f));
                    outB[(size_t)row * N + col] = (bf16)v;
                } else if (EPI == 2) {
                    outF[(size_t)row * N + col] = res[(size_t)row * N + col] + v;
                } else {
                    outF[(size_t)row * N + col] = res[(size_t)row * N + col] + v + bv;
                }
            }
        }
    }
}

// ---------------------------------------------------------------- 256x256 GEMM (gemmE, read-swizzle FIXED to <=2-way)
// 8 waves (2Mx4N), per-wave 128x64, BK=32, dbuf 2x32KB, vmcnt(4).
// LDS rows 64B; slot s of row r holds global 16B-unit s^((r>>1)&3);
// read slot = hi^((lo>>1)&3) -> 2-way max (free). Staging 4 lanes = 64B segment.
// EPI: 1 = +bias exact GELU bf16 out (only variant used)
template <int EPI>
__global__ __launch_bounds__(512, 2) void gemmE(const bf16* __restrict__ A,
                                                const bf16* __restrict__ B,
                                                void* __restrict__ OutP,
                                                const float* __restrict__ bias,
                                                int M, int N, int K) {
    extern __shared__ __align__(16) char lds[];
    const int tid = threadIdx.x;
    const int lane = tid & 63;
    const int w = tid >> 6, wr = w >> 2, wc = w & 3;
    const int lo = lane & 15, hi = lane >> 4;

    const int nwg = gridDim.x;
    const int bid = blockIdx.x;
    const int q = nwg >> 3, r = nwg & 7, xcd = bid & 7, off = bid >> 3;
    const int s = (xcd < r ? xcd * (q + 1) : r * (q + 1) + (xcd - r) * q) + off;
    const int MB = M / 256;
    const int per = MB * 4;
    const int grp = s / per, t2 = s - grp * per;
    const int brow = (t2 % MB) * 256;
    const int bcol = (grp * 4 + t2 / MB) * 256;

    // staging: thread t -> row t>>2 (+128), 16B-unit (t&3)^((t>>3)&3); dest linear
    const int srow = tid >> 2;
    const int scol = ((tid & 3) ^ ((tid >> 3) & 3)) * 8;
    const bf16* Ag = A + (size_t)(brow + srow) * K + scol;
    const bf16* Bg = B + (size_t)(bcol + srow) * K + scol;
    const size_t R128 = (size_t)128 * K;
    char* d0 = lds + tid * 16;

    auto stage = [&](int bf, int kt) {
        char* d = d0 + bf * 32768;
        gload_lds16(Ag + kt * 32, d);
        gload_lds16(Ag + R128 + kt * 32, d + 8192);
        gload_lds16(Bg + kt * 32, d + 16384);
        gload_lds16(Bg + R128 + kt * 32, d + 24576);
    };

    f32x4 acc[8][4] = {};
    const int NT = K >> 5;
    const int xsl = (hi ^ ((lo >> 1) & 3)) << 4;   // fixed: 2-way max

    stage(0, 0);
    #pragma unroll 1
    for (int kt = 0; kt < NT; ++kt) {
        const int cur = kt & 1;
        if (kt + 1 < NT) {
            stage(cur ^ 1, kt + 1);
            asm volatile("s_waitcnt vmcnt(4)" ::: "memory");
        } else {
            asm volatile("s_waitcnt vmcnt(0)" ::: "memory");
        }
        __builtin_amdgcn_s_barrier();

        const char* ab = lds + cur * 32768;
        const char* bb = ab + 16384;
        bf16x8 af[8], bv[4];
        #pragma unroll
        for (int m = 0; m < 4; ++m)
            af[m] = *(const bf16x8*)(ab + (wr * 128 + m * 16 + lo) * 64 + xsl);
        #pragma unroll
        for (int n = 0; n < 4; ++n)
            bv[n] = *(const bf16x8*)(bb + (wc * 64 + n * 16 + lo) * 64 + xsl);
        __builtin_amdgcn_s_setprio(1);
        #pragma unroll
        for (int m = 0; m < 4; ++m)
            #pragma unroll
            for (int n = 0; n < 4; ++n)
                acc[m][n] = __builtin_amdgcn_mfma_f32_16x16x32_bf16(af[m], bv[n], acc[m][n], 0, 0, 0);
        __builtin_amdgcn_s_setprio(0);
        #pragma unroll
        for (int m = 4; m < 8; ++m)
            af[m] = *(const bf16x8*)(ab + (wr * 128 + m * 16 + lo) * 64 + xsl);
        __builtin_amdgcn_s_setprio(1);
        #pragma unroll
        for (int m = 4; m < 8; ++m)
            #pragma unroll
            for (int n = 0; n < 4; ++n)
                acc[m][n] = __builtin_amdgcn_mfma_f32_16x16x32_bf16(af[m], bv[n], acc[m][n], 0, 0, 0);
        __builtin_amdgcn_s_setprio(0);
        __builtin_amdgcn_s_barrier();
    }

    bf16* outB = (bf16*)OutP;
    #pragma unroll
    for (int n = 0; n < 4; ++n) {
        const int col = bcol + wc * 64 + n * 16 + lo;
        float bv2 = bias[col];
        #pragma unroll
        for (int m = 0; m < 8; ++m) {
            #pragma unroll
            for (int rr = 0; rr < 4; ++rr) {
                const int row = brow + wr * 128 + m * 16 + hi * 4 + rr;
                float v = acc[m][n][rr] + bv2;
                v = 0.5f * v * (1.0f + erff(v * 0.70710678118654752f));
                outB[(size_t)row * N + col] = (bf16)v;
            }
        }
    }
}

// ---------------------------------------------------------------- RoPE + GQA scatter (Q, K only; V handled by vtrans)
__global__ __launch_bounds__(256) void rope_scatter(const bf16* __restrict__ qkv,
                                                    const float* __restrict__ cosb,
                                                    const float* __restrict__ sinb,
                                                    bf16* __restrict__ Q,
                                                    bf16* __restrict__ Kg) {
    const int tid = threadIdx.x;
    const int row = blockIdx.x;          // b*T + t
    const int b = row >> 11, t = row & 2047;
    const bf16* src = qkv + (size_t)row * 3072;
    #pragma unroll
    for (int i = tid; i < 1280; i += 256) {
        int slot = i >> 6;               // 0..19 = g*5 + m  (m: 0-3 Q, 4 K)
        int d = i & 63;
        int g = slot / 5, m = slot - g * 5;
        int msrc = g * 6 + m;            // memory slot in qkv row
        float v1 = (float)src[msrc * 128 + d];
        float v2 = (float)src[msrc * 128 + d + 64];
        float c1 = cosb[t * 128 + d],      s1 = sinb[t * 128 + d];
        float c2 = cosb[t * 128 + d + 64], s2 = sinb[t * 128 + d + 64];
        float o1 = v1 * c1 - v2 * s1;
        float o2 = v2 * c2 + v1 * s2;
        if (m < 4) {
            int hh = g * 4 + m;
            size_t base = ((size_t)(b * 16 + hh) * 2048 + t) * 128;
            Q[base + d] = (bf16)o1;
            Q[base + d + 64] = (bf16)o2;
        } else {
            size_t base = ((size_t)(b * 4 + g) * 2048 + t) * 128;
            Kg[base + d] = (bf16)o1;
            Kg[base + d + 64] = (bf16)o2;
        }
    }
}

// ---------------------------------------------------------------- V transpose: qkvo -> Vt (B,4,128,T)
// Reads 128B-coalesced columns (lane d contiguous), writes 16B chunks along t.
__global__ __launch_bounds__(256) void vtrans(const bf16* __restrict__ qkvo,
                                              bf16* __restrict__ Vt) {
    const int tid = threadIdx.x;
    const int t0 = blockIdx.x * 64;      // 32 t-tiles
    const int z  = blockIdx.y;           // b*4+g (8)
    const int b = z >> 2, g = z & 3;
    const int d = tid & 127;
    const int th = tid >> 7;             // t-half (0/1 -> 32 t each)
    const bf16* src = qkvo + (size_t)(b * 2048 + t0 + th * 32) * 3072 + g * 768 + 640 + d;
    bf16* dst = Vt + ((size_t)z * 128 + d) * 2048 + t0 + th * 32;
    #pragma unroll
    for (int c = 0; c < 4; ++c) {
        bf16x8 v;
        #pragma unroll
        for (int j = 0; j < 8; ++j)
            v[j] = src[(size_t)(c * 8 + j) * 3072];
        *(bf16x8*)(dst + c * 8) = v;
    }
}

// ---------------------------------------------------------------- causal flash attention
// Balanced: block bx handles q-tiles {bx, 31-bx} -> every block does 33 KV-tile steps.
__global__ __launch_bounds__(256) void attn_kernel(const bf16* __restrict__ Q,
                                                   const bf16* __restrict__ Kg,
                                                   const bf16* __restrict__ Vt,
                                                   bf16* __restrict__ Y) {
    __shared__ __align__(16) bf16 Ks[64 * 128];
    __shared__ __align__(16) bf16 Vs[128 * 64];
    __shared__ __align__(16) bf16 Ps[4][16 * 80];

    const int tid = threadIdx.x;
    const int lane = tid & 63, w = tid >> 6;
    const int lo = lane & 15, hi = lane >> 4;
    const int bh = blockIdx.y;
    const int b = bh >> 4, h = bh & 15;
    const int g = h >> 2;

    const bf16* Kbase = Kg + (size_t)(b * 4 + g) * 2048 * 128;
    const bf16* Vbase = Vt + (size_t)(b * 4 + g) * 128 * 2048;
    const float scale = 0.08838834764831845f;
    bf16* pw = &Ps[w][0];

    #pragma unroll 1
    for (int pass = 0; pass < 2; ++pass) {
        const int qt = pass ? 31 - (int)blockIdx.x : (int)blockIdx.x;
        const int q0 = qt * 64;

        bf16x8 qf[4];
        {
            const size_t qbase = ((size_t)bh * 2048 + q0 + w * 16 + lo) * 128;
            #pragma unroll
            for (int dd = 0; dd < 4; ++dd)
                qf[dd] = *(const bf16x8*)(Q + qbase + dd * 32 + hi * 8);
        }

        float m_r[4], l_r[4];
        f32x4 oacc[8] = {};
        #pragma unroll
        for (int rr = 0; rr < 4; ++rr) { m_r[rr] = -1e30f; l_r[rr] = 0.f; }

        for (int kt = 0; kt <= qt; ++kt) {
            #pragma unroll
            for (int it = 0; it < 4; ++it) {
                int ob = (it * 256 + tid) * 16;
                int rk = ob >> 8, cb = ob & 255;
                bf16x8 kv = *(const bf16x8*)(Kbase + (size_t)(kt * 64 + rk) * 128 + (cb >> 1));
                *(bf16x8*)((char*)Ks + rk * 256 + (cb ^ ((rk & 7) << 4))) = kv;
                int dv = ob >> 7, cv = ob & 127;
                bf16x8 vv = *(const bf16x8*)(Vbase + (size_t)dv * 2048 + kt * 64 + (cv >> 1));
                *(bf16x8*)((char*)Vs + dv * 128 + (cv ^ ((dv & 7) << 4))) = vv;
            }
            __syncthreads();

            f32x4 sj[4];
            #pragma unroll
            for (int j = 0; j < 4; ++j) {
                f32x4 a = {};
                int rk = j * 16 + lo;
                #pragma unroll
                for (int dd = 0; dd < 4; ++dd) {
                    int cb = dd * 64 + hi * 16;
                    bf16x8 kf = *(const bf16x8*)((const char*)Ks + rk * 256 + (cb ^ ((rk & 7) << 4)));
                    a = __builtin_amdgcn_mfma_f32_16x16x32_bf16(qf[dd], kf, a, 0, 0, 0);
                }
                sj[j] = a;
            }

            float sv[4][4];
            const bool diag = (kt == qt);
            #pragma unroll
            for (int j = 0; j < 4; ++j)
                #pragma unroll
                for (int rr = 0; rr < 4; ++rr) {
                    float v = sj[j][rr] * scale;
                    if (diag) {
                        int tg = kt * 64 + j * 16 + lo;
                        int qg = q0 + w * 16 + hi * 4 + rr;
                        if (tg > qg) v = -1e30f;
                    }
                    sv[j][rr] = v;
                }

            float mx[4];
            #pragma unroll
            for (int rr = 0; rr < 4; ++rr) {
                float m0 = fmaxf(fmaxf(sv[0][rr], sv[1][rr]), fmaxf(sv[2][rr], sv[3][rr]));
                #pragma unroll
                for (int off = 8; off; off >>= 1) m0 = fmaxf(m0, __shfl_xor(m0, off, 16));
                mx[rr] = m0;
            }
            float p[4][4];
            float rs[4], al[4];
            #pragma unroll
            for (int rr = 0; rr < 4; ++rr) {
                float mnew = fmaxf(m_r[rr], mx[rr]);
                #pragma unroll
                for (int j = 0; j < 4; ++j)
                    p[j][rr] = exp2f((sv[j][rr] - mnew) * LOG2E);
                float s0 = p[0][rr] + p[1][rr] + p[2][rr] + p[3][rr];
                #pragma unroll
                for (int off = 8; off; off >>= 1) s0 += __shfl_xor(s0, off, 16);
                rs[rr] = s0;
                al[rr] = exp2f((m_r[rr] - mnew) * LOG2E);
                l_r[rr] = l_r[rr] * al[rr] + rs[rr];
                m_r[rr] = mnew;
            }
            #pragma unroll
            for (int dn = 0; dn < 8; ++dn)
                #pragma unroll
                for (int rr = 0; rr < 4; ++rr) oacc[dn][rr] *= al[rr];

            #pragma unroll
            for (int j = 0; j < 4; ++j)
                #pragma unroll
                for (int rr = 0; rr < 4; ++rr)
                    pw[(hi * 4 + rr) * 80 + j * 16 + lo] = (bf16)p[j][rr];

            #pragma unroll
            for (int tc = 0; tc < 2; ++tc) {
                bf16x8 pf = *(const bf16x8*)(pw + lo * 80 + tc * 32 + hi * 8);
                #pragma unroll
                for (int dn = 0; dn < 8; ++dn) {
                    int rv = dn * 16 + lo;
                    int cv = tc * 64 + hi * 16;
                    bf16x8 vf = *(const bf16x8*)((const char*)Vs + rv * 128 + (cv ^ ((rv & 7) << 4)));
                    oacc[dn] = __builtin_amdgcn_mfma_f32_16x16x32_bf16(pf, vf, oacc[dn], 0, 0, 0);
                }
            }
            __syncthreads();
        }

        #pragma unroll
        for (int dn = 0; dn < 8; ++dn)
            #pragma unroll
            for (int rr = 0; rr < 4; ++rr) {
                int qg = q0 + w * 16 + hi * 4 + rr;
                Y[((size_t)b * 2048 + qg) * 2048 + h * 128 + dn * 16 + lo] =
                    (bf16)(oacc[dn][rr] / l_r[rr]);
            }
    }
}

// ---------------------------------------------------------------- launch
extern "C" void kernel_launch(void* const* d_in, const int* in_sizes, int n_in,
                              void* d_out, int out_size, void* d_ws, size_t ws_size,
                              hipStream_t stream) {
    const float* x      = (const float*)d_in[0];
    const float* cosb   = (const float*)d_in[1];
    const float* sinb   = (const float*)d_in[2];
    const float* ln1_w  = (const float*)d_in[4];
    const float* ln1_b  = (const float*)d_in[5];
    const float* qkv_w  = (const float*)d_in[6];
    const float* proj_w = (const float*)d_in[7];
    const float* ln2_w  = (const float*)d_in[8];
    const float* ln2_b  = (const float*)d_in[9];
    const float* fc1_w  = (const float*)d_in[10];
    const float* fc1_b  = (const float*)d_in[11];
    const float* fc2_w  = (const float*)d_in[12];
    const float* fc2_b  = (const float*)d_in[13];
    float* out = (float*)d_out;

    char* ws = (char*)d_ws;
    bf16*  w_qkv  = (bf16*)(ws + 0ull);            // 3072x2048
    bf16*  w_proj = (bf16*)(ws + 12582912ull);     // 2048x2048
    bf16*  w_fc1  = (bf16*)(ws + 20971520ull);     // 8192x2048
    bf16*  w_fc2  = (bf16*)(ws + 54525952ull);     // 2048x8192
    float* x2     = (float*)(ws + 88080384ull);    // 4096x2048 f32
    bf16*  lnout  = (bf16*)(ws + 121634816ull);    // 4096x2048
    char*  R      = ws + 138412032ull;             // aliased region (67.1 MB)
    bf16*  qkvo = (bf16*)(R);                      // 4096x3072
    bf16*  Qb   = (bf16*)(R + 25165824ull);        // 2,16,2048,128
    bf16*  Kb   = (bf16*)(R + 41943040ull);        // 2,4,2048,128
    bf16*  Vtb  = (bf16*)(R + 46137344ull);        // 2,4,128,2048
    bf16*  Yb   = (bf16*)(R + 50331648ull);        // 4096x2048
    bf16*  mlp  = (bf16*)(R);                      // 4096x8192 (aliases all above)

    constexpr int LDSE = 65536;

    cvt_bf16<<<6144,  256, 0, stream>>>(qkv_w,  w_qkv,  3072 * 2048);
    cvt_bf16<<<4096,  256, 0, stream>>>(proj_w, w_proj, 2048 * 2048);
    cvt_bf16<<<16384, 256, 0, stream>>>(fc1_w,  w_fc1,  8192 * 2048);
    cvt_bf16<<<16384, 256, 0, stream>>>(fc2_w,  w_fc2,  2048 * 8192);

    ln_kernel<<<4096, 256, 0, stream>>>(x, ln1_w, ln1_b, lnout);

    gemmB<0><<<768, 512, 0, stream>>>(lnout, w_qkv, qkvo, nullptr, nullptr,
                                      4096, 3072, 2048);

    rope_scatter<<<4096, 256, 0, stream>>>(qkvo, cosb, sinb, Qb, Kb);
    vtrans<<<dim3(32, 8), 256, 0, stream>>>(qkvo, Vtb);

    attn_kernel<<<dim3(16, 32), 256, 0, stream>>>(Qb, Kb, Vtb, Yb);

    gemmB<2><<<512, 512, 0, stream>>>(Yb, w_proj, x2, nullptr, x,
                                      4096, 2048, 2048);

    ln_kernel<<<4096, 256, 0, stream>>>(x2, ln2_w, ln2_b, lnout);

    gemmE<1><<<512, 512, LDSE, stream>>>(lnout, w_fc1, mlp, fc1_b,
                                         4096, 8192, 2048);

    gemmB<3><<<512, 512, 0, stream>>>(mlp, w_fc2, out, fc2_b, x2,
                                      4096, 2048, 8192);
}

// Round 12
// 671.144 us; speedup vs baseline: 1.1935x; 1.0528x over previous
//
#include <hip/hip_runtime.h>

typedef __bf16 bf16;
typedef __bf16 bf16x8 __attribute__((ext_vector_type(8)));
typedef __bf16 bf16x4 __attribute__((ext_vector_type(4)));
typedef float  f32x4  __attribute__((ext_vector_type(4)));

#define LOG2E 1.4426950408889634f

// ---------------------------------------------------------------- helpers
__device__ __forceinline__ void gload_lds16(const void* g, void* l) {
    __builtin_amdgcn_global_load_lds(
        (__attribute__((address_space(1))) const void*)g,
        (__attribute__((address_space(3))) void*)l, 16, 0, 0);
}

// ---------------------------------------------------------------- f32 -> bf16 weight convert
__global__ __launch_bounds__(256) void cvt_bf16(const float* __restrict__ src,
                                                bf16* __restrict__ dst, int n) {
    int i = (blockIdx.x * 256 + threadIdx.x) * 4;
    if (i + 3 < n) {
        float4 v = *(const float4*)(src + i);
        bf16x4 o;
        o[0] = (bf16)v.x; o[1] = (bf16)v.y; o[2] = (bf16)v.z; o[3] = (bf16)v.w;
        *(bf16x4*)(dst + i) = o;
    }
}

// ---------------------------------------------------------------- LayerNorm (f32 in, bf16 out), row = 2048
__global__ __launch_bounds__(256) void ln_kernel(const float* __restrict__ x,
                                                 const float* __restrict__ wgt,
                                                 const float* __restrict__ bias,
                                                 bf16* __restrict__ out) {
    __shared__ float red[8];
    const int tid = threadIdx.x;
    const int lane = tid & 63, w = tid >> 6;
    const size_t row = blockIdx.x;
    const float4* xr = (const float4*)(x + row * 2048);
    float4 v0 = xr[tid];
    float4 v1 = xr[tid + 256];
    float s = v0.x + v0.y + v0.z + v0.w + v1.x + v1.y + v1.z + v1.w;
    float q = v0.x*v0.x + v0.y*v0.y + v0.z*v0.z + v0.w*v0.w
            + v1.x*v1.x + v1.y*v1.y + v1.z*v1.z + v1.w*v1.w;
    #pragma unroll
    for (int off = 32; off; off >>= 1) {
        s += __shfl_xor(s, off);
        q += __shfl_xor(q, off);
    }
    if (lane == 0) { red[w] = s; red[4 + w] = q; }
    __syncthreads();
    float S  = red[0] + red[1] + red[2] + red[3];
    float Q2 = red[4] + red[5] + red[6] + red[7];
    float mu = S * (1.0f / 2048.0f);
    float var = Q2 * (1.0f / 2048.0f) - mu * mu;
    float rstd = rsqrtf(var + 1e-5f);

    bf16* orow = out + row * 2048;
    int c0 = tid * 4;
    float vv[8] = {v0.x, v0.y, v0.z, v0.w, v1.x, v1.y, v1.z, v1.w};
    bf16x4 o;
    #pragma unroll
    for (int k = 0; k < 4; ++k)
        o[k] = (bf16)((vv[k] - mu) * rstd * wgt[c0 + k] + bias[c0 + k]);
    *(bf16x4*)(orow + c0) = o;
    #pragma unroll
    for (int k = 0; k < 4; ++k)
        o[k] = (bf16)((vv[4 + k] - mu) * rstd * wgt[1024 + c0 + k] + bias[1024 + c0 + k]);
    *(bf16x4*)(orow + 1024 + c0) = o;
}

// ---------------------------------------------------------------- 128x128 GEMM (session-best gemmB; conflicts measured 0)
// 8 waves (4x2), 512 threads, BK=64, dbuf 2x32KB, vmcnt(4), XOR unit-swizzle.
// EPI: 0 bf16 | 1 +bias GELU bf16 | 2 res+acc f32 | 3 res+acc+bias f32
template <int EPI>
__global__ __launch_bounds__(512, 4) void gemmB(const bf16* __restrict__ A,
                                                const bf16* __restrict__ B,
                                                void* __restrict__ OutP,
                                                const float* __restrict__ bias,
                                                const float* __restrict__ res,
                                                int M, int N, int K) {
    __shared__ __align__(16) char lds[65536];
    const int tid = threadIdx.x;
    const int lane = tid & 63;
    const int w = tid >> 6, wr = w >> 1, wc = w & 1;
    const int lo = lane & 15, hi = lane >> 4;

    const int nwg = gridDim.x;
    const int bid = blockIdx.x;
    const int q = nwg >> 3, r = nwg & 7, xcd = bid & 7, off = bid >> 3;
    const int s = (xcd < r ? xcd * (q + 1) : r * (q + 1) + (xcd - r) * q) + off;
    const int MB = M / 128;
    const int per = MB * 4;
    const int grp = s / per, t2 = s - grp * per;
    const int brow = (t2 % MB) * 128;
    const int bcol = (grp * 4 + t2 / MB) * 128;

    const int sr = tid >> 3;
    const int su = (tid & 7) ^ (sr & 7);
    const bf16* Ag = A + (size_t)(brow + sr) * K + su * 8;
    const bf16* Bg = B + (size_t)(bcol + sr) * K + su * 8;
    const size_t K64 = (size_t)64 * K;
    char* dst0 = lds + tid * 16;

    auto stage = [&](int bf, int kt) {
        char* d = dst0 + bf * 32768;
        gload_lds16(Ag + kt * 64, d);
        gload_lds16(Ag + K64 + kt * 64, d + 8192);
        gload_lds16(Bg + kt * 64, d + 16384);
        gload_lds16(Bg + K64 + kt * 64, d + 24576);
    };

    f32x4 acc[2][4] = {};
    const int NT = K >> 6;

    stage(0, 0);
    for (int kt = 0; kt < NT; ++kt) {
        const int cur = kt & 1;
        if (kt + 1 < NT) {
            stage(cur ^ 1, kt + 1);
            asm volatile("s_waitcnt vmcnt(4)" ::: "memory");
        } else {
            asm volatile("s_waitcnt vmcnt(0)" ::: "memory");
        }
        __builtin_amdgcn_s_barrier();

        const char* ab = lds + cur * 32768;
        const char* bb = ab + 16384;
        bf16x8 af[2][2], bfv[4][2];
        #pragma unroll
        for (int m = 0; m < 2; ++m) {
            const int rA = wr * 32 + m * 16 + lo;
            #pragma unroll
            for (int ks = 0; ks < 2; ++ks)
                af[m][ks] = *(const bf16x8*)(ab + rA * 128 + (((ks * 4 + hi) ^ (lo & 7)) << 4));
        }
        #pragma unroll
        for (int n = 0; n < 4; ++n) {
            const int rB = wc * 64 + n * 16 + lo;
            #pragma unroll
            for (int ks = 0; ks < 2; ++ks)
                bfv[n][ks] = *(const bf16x8*)(bb + rB * 128 + (((ks * 4 + hi) ^ (lo & 7)) << 4));
        }
        __builtin_amdgcn_s_setprio(1);
        #pragma unroll
        for (int m = 0; m < 2; ++m)
            #pragma unroll
            for (int n = 0; n < 4; ++n)
                #pragma unroll
                for (int ks = 0; ks < 2; ++ks)
                    acc[m][n] = __builtin_amdgcn_mfma_f32_16x16x32_bf16(af[m][ks], bfv[n][ks], acc[m][n], 0, 0, 0);
        __builtin_amdgcn_s_setprio(0);
        __builtin_amdgcn_s_barrier();
    }

    float* outF = (float*)OutP;
    bf16*  outB = (bf16*)OutP;
    #pragma unroll
    for (int n = 0; n < 4; ++n) {
        const int col = bcol + wc * 64 + n * 16 + lo;
        float bv = 0.f;
        if (EPI == 1 || EPI == 3) bv = bias[col];
        #pragma unroll
        for (int m = 0; m < 2; ++m) {
            #pragma unroll
            for (int rr = 0; rr < 4; ++rr) {
                const int row = brow + wr * 32 + m * 16 + hi * 4 + rr;
                float v = acc[m][n][rr];
                if (EPI == 0) {
                    outB[(size_t)row * N + col] = (bf16)v;
                } else if (EPI == 1) {
                    v += bv;
                    v = 0.5f * v * (1.0f + erff(v * 0.70710678118654752f));
                    outB[(size_t)row * N + col] = (bf16)v;
                } else if (EPI == 2) {
                    outF[(size_t)row * N + col] = res[(size_t)row * N + col] + v;
                } else {
                    outF[(size_t)row * N + col] = res[(size_t)row * N + col] + v + bv;
                }
            }
        }
    }
}

// ---------------------------------------------------------------- RoPE + GQA scatter (Q, K only; V handled by vtrans)
__global__ __launch_bounds__(256) void rope_scatter(const bf16* __restrict__ qkv,
                                                    const float* __restrict__ cosb,
                                                    const float* __restrict__ sinb,
                                                    bf16* __restrict__ Q,
                                                    bf16* __restrict__ Kg) {
    const int tid = threadIdx.x;
    const int row = blockIdx.x;          // b*T + t
    const int b = row >> 11, t = row & 2047;
    const bf16* src = qkv + (size_t)row * 3072;
    #pragma unroll
    for (int i = tid; i < 1280; i += 256) {
        int slot = i >> 6;               // 0..19 = g*5 + m  (m: 0-3 Q, 4 K)
        int d = i & 63;
        int g = slot / 5, m = slot - g * 5;
        int msrc = g * 6 + m;            // memory slot in qkv row
        float v1 = (float)src[msrc * 128 + d];
        float v2 = (float)src[msrc * 128 + d + 64];
        float c1 = cosb[t * 128 + d],      s1 = sinb[t * 128 + d];
        float c2 = cosb[t * 128 + d + 64], s2 = sinb[t * 128 + d + 64];
        float o1 = v1 * c1 - v2 * s1;
        float o2 = v2 * c2 + v1 * s2;
        if (m < 4) {
            int hh = g * 4 + m;
            size_t base = ((size_t)(b * 16 + hh) * 2048 + t) * 128;
            Q[base + d] = (bf16)o1;
            Q[base + d + 64] = (bf16)o2;
        } else {
            size_t base = ((size_t)(b * 4 + g) * 2048 + t) * 128;
            Kg[base + d] = (bf16)o1;
            Kg[base + d + 64] = (bf16)o2;
        }
    }
}

// ---------------------------------------------------------------- V transpose: qkvo -> Vt (B,4,128,T)
__global__ __launch_bounds__(256) void vtrans(const bf16* __restrict__ qkvo,
                                              bf16* __restrict__ Vt) {
    const int tid = threadIdx.x;
    const int t0 = blockIdx.x * 64;      // 32 t-tiles
    const int z  = blockIdx.y;           // b*4+g (8)
    const int b = z >> 2, g = z & 3;
    const int d = tid & 127;
    const int th = tid >> 7;             // t-half (0/1 -> 32 t each)
    const bf16* src = qkvo + (size_t)(b * 2048 + t0 + th * 32) * 3072 + g * 768 + 640 + d;
    bf16* dst = Vt + ((size_t)z * 128 + d) * 2048 + t0 + th * 32;
    #pragma unroll
    for (int c = 0; c < 4; ++c) {
        bf16x8 v;
        #pragma unroll
        for (int j = 0; j < 8; ++j)
            v[j] = src[(size_t)(c * 8 + j) * 3072];
        *(bf16x8*)(dst + c * 8) = v;
    }
}

// ---------------------------------------------------------------- causal flash attention
// Balanced pair {bx, 31-bx}; K/V double-buffered in LDS with T14 async staging:
// loads for kt+1 issued into REGISTERS before compute of kt (HBM latency hides
// under QK^T/softmax/PV), written to buf^1 after compute, ONE barrier per step.
// T13 defer-max: skip O-rescale while tile max grows < 8 (P bounded by e^8).
__global__ __launch_bounds__(256) void attn_kernel(const bf16* __restrict__ Q,
                                                   const bf16* __restrict__ Kg,
                                                   const bf16* __restrict__ Vt,
                                                   bf16* __restrict__ Y) {
    __shared__ __align__(16) bf16 Ks[2][64 * 128];
    __shared__ __align__(16) bf16 Vs[2][128 * 64];
    __shared__ __align__(16) bf16 Ps[4][16 * 80];

    const int tid = threadIdx.x;
    const int lane = tid & 63, w = tid >> 6;
    const int lo = lane & 15, hi = lane >> 4;
    const int bh = blockIdx.y;
    const int b = bh >> 4, h = bh & 15;
    const int g = h >> 2;

    const bf16* Kbase = Kg + (size_t)(b * 4 + g) * 2048 * 128;
    const bf16* Vbase = Vt + (size_t)(b * 4 + g) * 128 * 2048;
    const float scale = 0.08838834764831845f;
    bf16* pw = &Ps[w][0];

    bf16x8 kreg[4], vreg[4];

    #pragma unroll 1
    for (int pass = 0; pass < 2; ++pass) {
        const int qt = pass ? 31 - (int)blockIdx.x : (int)blockIdx.x;
        const int q0 = qt * 64;

        bf16x8 qf[4];
        {
            const size_t qbase = ((size_t)bh * 2048 + q0 + w * 16 + lo) * 128;
            #pragma unroll
            for (int dd = 0; dd < 4; ++dd)
                qf[dd] = *(const bf16x8*)(Q + qbase + dd * 32 + hi * 8);
        }

        float m_r[4], l_r[4];
        f32x4 oacc[8] = {};
        #pragma unroll
        for (int rr = 0; rr < 4; ++rr) { m_r[rr] = -1e30f; l_r[rr] = 0.f; }

        // ---- prologue: tile 0 -> buf 0
        #pragma unroll
        for (int it = 0; it < 4; ++it) {
            int ob = (it * 256 + tid) * 16;
            int rk = ob >> 8, cb = ob & 255;
            kreg[it] = *(const bf16x8*)(Kbase + (size_t)rk * 128 + (cb >> 1));
            int dv = ob >> 7, cv = ob & 127;
            vreg[it] = *(const bf16x8*)(Vbase + (size_t)dv * 2048 + (cv >> 1));
        }
        #pragma unroll
        for (int it = 0; it < 4; ++it) {
            int ob = (it * 256 + tid) * 16;
            int rk = ob >> 8, cb = ob & 255;
            *(bf16x8*)((char*)Ks[0] + rk * 256 + (cb ^ ((rk & 7) << 4))) = kreg[it];
            int dv = ob >> 7, cv = ob & 127;
            *(bf16x8*)((char*)Vs[0] + dv * 128 + (cv ^ ((dv & 7) << 4))) = vreg[it];
        }
        __syncthreads();
        int cur = 0;

        for (int kt = 0; kt <= qt; ++kt) {
            const bool pf = (kt < qt);
            // ---- issue next tile's global loads EARLY (latency hides under compute)
            if (pf) {
                #pragma unroll
                for (int it = 0; it < 4; ++it) {
                    int ob = (it * 256 + tid) * 16;
                    int rk = ob >> 8, cb = ob & 255;
                    kreg[it] = *(const bf16x8*)(Kbase + (size_t)((kt + 1) * 64 + rk) * 128 + (cb >> 1));
                    int dv = ob >> 7, cv = ob & 127;
                    vreg[it] = *(const bf16x8*)(Vbase + (size_t)dv * 2048 + (kt + 1) * 64 + (cv >> 1));
                }
            }

            const char* KsC = (const char*)Ks[cur];
            const char* VsC = (const char*)Vs[cur];

            // ---- S = Q K^T : 4 t-subtiles of 16
            f32x4 sj[4];
            #pragma unroll
            for (int j = 0; j < 4; ++j) {
                f32x4 a = {};
                int rk = j * 16 + lo;
                #pragma unroll
                for (int dd = 0; dd < 4; ++dd) {
                    int cb = dd * 64 + hi * 16;
                    bf16x8 kf = *(const bf16x8*)(KsC + rk * 256 + (cb ^ ((rk & 7) << 4)));
                    a = __builtin_amdgcn_mfma_f32_16x16x32_bf16(qf[dd], kf, a, 0, 0, 0);
                }
                sj[j] = a;
            }

            // ---- scale + causal mask
            float sv[4][4];
            const bool diag = (kt == qt);
            #pragma unroll
            for (int j = 0; j < 4; ++j)
                #pragma unroll
                for (int rr = 0; rr < 4; ++rr) {
                    float v = sj[j][rr] * scale;
                    if (diag) {
                        int tg = kt * 64 + j * 16 + lo;
                        int qg = q0 + w * 16 + hi * 4 + rr;
                        if (tg > qg) v = -1e30f;
                    }
                    sv[j][rr] = v;
                }

            // ---- tile max per row
            float mx[4];
            #pragma unroll
            for (int rr = 0; rr < 4; ++rr) {
                float m0 = fmaxf(fmaxf(sv[0][rr], sv[1][rr]), fmaxf(sv[2][rr], sv[3][rr]));
                #pragma unroll
                for (int off = 8; off; off >>= 1) m0 = fmaxf(m0, __shfl_xor(m0, off, 16));
                mx[rr] = m0;
            }

            // ---- defer-max: rescale only when max grew by > 8
            bool need = false;
            #pragma unroll
            for (int rr = 0; rr < 4; ++rr) need = need || (mx[rr] > m_r[rr] + 8.0f);
            if (__any(need)) {
                #pragma unroll
                for (int rr = 0; rr < 4; ++rr) {
                    float mnew = fmaxf(m_r[rr], mx[rr]);
                    float al = exp2f((m_r[rr] - mnew) * LOG2E);
                    l_r[rr] *= al;
                    m_r[rr] = mnew;
                    #pragma unroll
                    for (int dn = 0; dn < 8; ++dn) oacc[dn][rr] *= al;
                }
            }

            // ---- P = exp(S - m), row sums
            float p[4][4];
            #pragma unroll
            for (int rr = 0; rr < 4; ++rr) {
                #pragma unroll
                for (int j = 0; j < 4; ++j)
                    p[j][rr] = exp2f((sv[j][rr] - m_r[rr]) * LOG2E);
                float s0 = p[0][rr] + p[1][rr] + p[2][rr] + p[3][rr];
                #pragma unroll
                for (int off = 8; off; off >>= 1) s0 += __shfl_xor(s0, off, 16);
                l_r[rr] += s0;
            }

            // ---- write P to per-wave LDS [16 q][80 t]
            #pragma unroll
            for (int j = 0; j < 4; ++j)
                #pragma unroll
                for (int rr = 0; rr < 4; ++rr)
                    pw[(hi * 4 + rr) * 80 + j * 16 + lo] = (bf16)p[j][rr];

            // ---- O += P V
            #pragma unroll
            for (int tc = 0; tc < 2; ++tc) {
                bf16x8 pf2 = *(const bf16x8*)(pw + lo * 80 + tc * 32 + hi * 8);
                #pragma unroll
                for (int dn = 0; dn < 8; ++dn) {
                    int rv = dn * 16 + lo;
                    int cv = tc * 64 + hi * 16;
                    bf16x8 vf = *(const bf16x8*)(VsC + rv * 128 + (cv ^ ((rv & 7) << 4)));
                    oacc[dn] = __builtin_amdgcn_mfma_f32_16x16x32_bf16(pf2, vf, oacc[dn], 0, 0, 0);
                }
            }

            // ---- write next tile (regs -> other buffer), then single barrier
            if (pf) {
                #pragma unroll
                for (int it = 0; it < 4; ++it) {
                    int ob = (it * 256 + tid) * 16;
                    int rk = ob >> 8, cb = ob & 255;
                    *(bf16x8*)((char*)Ks[cur ^ 1] + rk * 256 + (cb ^ ((rk & 7) << 4))) = kreg[it];
                    int dv = ob >> 7, cv = ob & 127;
                    *(bf16x8*)((char*)Vs[cur ^ 1] + dv * 128 + (cv ^ ((dv & 7) << 4))) = vreg[it];
                }
            }
            __syncthreads();
            cur ^= 1;
        }

        // ---- epilogue: Y[(b, q, h*128 + d)] = O / l
        #pragma unroll
        for (int dn = 0; dn < 8; ++dn)
            #pragma unroll
            for (int rr = 0; rr < 4; ++rr) {
                int qg = q0 + w * 16 + hi * 4 + rr;
                Y[((size_t)b * 2048 + qg) * 2048 + h * 128 + dn * 16 + lo] =
                    (bf16)(oacc[dn][rr] / l_r[rr]);
            }
    }
}

// ---------------------------------------------------------------- launch
extern "C" void kernel_launch(void* const* d_in, const int* in_sizes, int n_in,
                              void* d_out, int out_size, void* d_ws, size_t ws_size,
                              hipStream_t stream) {
    const float* x      = (const float*)d_in[0];
    const float* cosb   = (const float*)d_in[1];
    const float* sinb   = (const float*)d_in[2];
    const float* ln1_w  = (const float*)d_in[4];
    const float* ln1_b  = (const float*)d_in[5];
    const float* qkv_w  = (const float*)d_in[6];
    const float* proj_w = (const float*)d_in[7];
    const float* ln2_w  = (const float*)d_in[8];
    const float* ln2_b  = (const float*)d_in[9];
    const float* fc1_w  = (const float*)d_in[10];
    const float* fc1_b  = (const float*)d_in[11];
    const float* fc2_w  = (const float*)d_in[12];
    const float* fc2_b  = (const float*)d_in[13];
    float* out = (float*)d_out;

    char* ws = (char*)d_ws;
    bf16*  w_qkv  = (bf16*)(ws + 0ull);            // 3072x2048
    bf16*  w_proj = (bf16*)(ws + 12582912ull);     // 2048x2048
    bf16*  w_fc1  = (bf16*)(ws + 20971520ull);     // 8192x2048
    bf16*  w_fc2  = (bf16*)(ws + 54525952ull);     // 2048x8192
    float* x2     = (float*)(ws + 88080384ull);    // 4096x2048 f32
    bf16*  lnout  = (bf16*)(ws + 121634816ull);    // 4096x2048
    char*  R      = ws + 138412032ull;             // aliased region (67.1 MB)
    bf16*  qkvo = (bf16*)(R);                      // 4096x3072
    bf16*  Qb   = (bf16*)(R + 25165824ull);        // 2,16,2048,128
    bf16*  Kb   = (bf16*)(R + 41943040ull);        // 2,4,2048,128
    bf16*  Vtb  = (bf16*)(R + 46137344ull);        // 2,4,128,2048
    bf16*  Yb   = (bf16*)(R + 50331648ull);        // 4096x2048
    bf16*  mlp  = (bf16*)(R);                      // 4096x8192 (aliases all above)

    cvt_bf16<<<6144,  256, 0, stream>>>(qkv_w,  w_qkv,  3072 * 2048);
    cvt_bf16<<<4096,  256, 0, stream>>>(proj_w, w_proj, 2048 * 2048);
    cvt_bf16<<<16384, 256, 0, stream>>>(fc1_w,  w_fc1,  8192 * 2048);
    cvt_bf16<<<16384, 256, 0, stream>>>(fc2_w,  w_fc2,  2048 * 8192);

    ln_kernel<<<4096, 256, 0, stream>>>(x, ln1_w, ln1_b, lnout);

    gemmB<0><<<768, 512, 0, stream>>>(lnout, w_qkv, qkvo, nullptr, nullptr,
                                      4096, 3072, 2048);

    rope_scatter<<<4096, 256, 0, stream>>>(qkvo, cosb, sinb, Qb, Kb);
    vtrans<<<dim3(32, 8), 256, 0, stream>>>(qkvo, Vtb);

    attn_kernel<<<dim3(16, 32), 256, 0, stream>>>(Qb, Kb, Vtb, Yb);

    gemmB<2><<<512, 512, 0, stream>>>(Yb, w_proj, x2, nullptr, x,
                                      4096, 2048, 2048);

    ln_kernel<<<4096, 256, 0, stream>>>(x2, ln2_w, ln2_b, lnout);

    gemmB<1><<<2048, 512, 0, stream>>>(lnout, w_fc1, mlp, fc1_b, nullptr,
                                       4096, 8192, 2048);

    gemmB<3><<<512, 512, 0, stream>>>(mlp, w_fc2, out, fc2_b, x2,
                                      4096, 2048, 8192);
}

// Round 13
// 584.138 us; speedup vs baseline: 1.3713x; 1.1489x over previous
//
#include <hip/hip_runtime.h>

typedef __bf16 bf16;
typedef __bf16 bf16x8 __attribute__((ext_vector_type(8)));
typedef __bf16 bf16x4 __attribute__((ext_vector_type(4)));
typedef float  f32x4  __attribute__((ext_vector_type(4)));

#define LOG2E 1.4426950408889634f

// ---------------------------------------------------------------- helpers
__device__ __forceinline__ void gload_lds16(const void* g, void* l) {
    __builtin_amdgcn_global_load_lds(
        (__attribute__((address_space(1))) const void*)g,
        (__attribute__((address_space(3))) void*)l, 16, 0, 0);
}

// ---------------------------------------------------------------- f32 -> bf16 weight convert
__global__ __launch_bounds__(256) void cvt_bf16(const float* __restrict__ src,
                                                bf16* __restrict__ dst, int n) {
    int i = (blockIdx.x * 256 + threadIdx.x) * 4;
    if (i + 3 < n) {
        float4 v = *(const float4*)(src + i);
        bf16x4 o;
        o[0] = (bf16)v.x; o[1] = (bf16)v.y; o[2] = (bf16)v.z; o[3] = (bf16)v.w;
        *(bf16x4*)(dst + i) = o;
    }
}

// ---------------------------------------------------------------- LayerNorm (f32 in, bf16 out), row = 2048
__global__ __launch_bounds__(256) void ln_kernel(const float* __restrict__ x,
                                                 const float* __restrict__ wgt,
                                                 const float* __restrict__ bias,
                                                 bf16* __restrict__ out) {
    __shared__ float red[8];
    const int tid = threadIdx.x;
    const int lane = tid & 63, w = tid >> 6;
    const size_t row = blockIdx.x;
    const float4* xr = (const float4*)(x + row * 2048);
    float4 v0 = xr[tid];
    float4 v1 = xr[tid + 256];
    float s = v0.x + v0.y + v0.z + v0.w + v1.x + v1.y + v1.z + v1.w;
    float q = v0.x*v0.x + v0.y*v0.y + v0.z*v0.z + v0.w*v0.w
            + v1.x*v1.x + v1.y*v1.y + v1.z*v1.z + v1.w*v1.w;
    #pragma unroll
    for (int off = 32; off; off >>= 1) {
        s += __shfl_xor(s, off);
        q += __shfl_xor(q, off);
    }
    if (lane == 0) { red[w] = s; red[4 + w] = q; }
    __syncthreads();
    float S  = red[0] + red[1] + red[2] + red[3];
    float Q2 = red[4] + red[5] + red[6] + red[7];
    float mu = S * (1.0f / 2048.0f);
    float var = Q2 * (1.0f / 2048.0f) - mu * mu;
    float rstd = rsqrtf(var + 1e-5f);

    bf16* orow = out + row * 2048;
    int c0 = tid * 4;
    float vv[8] = {v0.x, v0.y, v0.z, v0.w, v1.x, v1.y, v1.z, v1.w};
    bf16x4 o;
    #pragma unroll
    for (int k = 0; k < 4; ++k)
        o[k] = (bf16)((vv[k] - mu) * rstd * wgt[c0 + k] + bias[c0 + k]);
    *(bf16x4*)(orow + c0) = o;
    #pragma unroll
    for (int k = 0; k < 4; ++k)
        o[k] = (bf16)((vv[4 + k] - mu) * rstd * wgt[1024 + c0 + k] + bias[1024 + c0 + k]);
    *(bf16x4*)(orow + 1024 + c0) = o;
}

// ---------------------------------------------------------------- 128x128 GEMM (session-best gemmB + 8x8 L2 block-squares)
// 8 waves (4x2), 512 threads, BK=64, dbuf 2x32KB, vmcnt(4), XOR unit-swizzle.
// Block order: XCD-bijective chunks, inside each chunk 8x8 block-squares
// (M-major square order within a column band). An XCD's 64 co-resident blocks
// (32 CU x 2) = one square -> 8 A-panels + 8 B-panels shared 8-way via its L2:
// staging loads hit L2 (~200cyc) instead of L3/HBM (~600-900cyc).
// EPI: 0 bf16 | 1 +bias GELU bf16 | 2 res+acc f32 | 3 res+acc+bias f32
template <int EPI>
__global__ __launch_bounds__(512, 4) void gemmB(const bf16* __restrict__ A,
                                                const bf16* __restrict__ B,
                                                void* __restrict__ OutP,
                                                const float* __restrict__ bias,
                                                const float* __restrict__ res,
                                                int M, int N, int K) {
    __shared__ __align__(16) char lds[65536];
    const int tid = threadIdx.x;
    const int lane = tid & 63;
    const int w = tid >> 6, wr = w >> 1, wc = w & 1;
    const int lo = lane & 15, hi = lane >> 4;

    // ---- block swizzle: XCD chunks -> 8x8 block-squares (M-major among squares)
    const int nwg = gridDim.x;
    const int bid = blockIdx.x;
    const int q = nwg >> 3, r = nwg & 7, xcd = bid & 7, off = bid >> 3;
    const int s = (xcd < r ? xcd * (q + 1) : r * (q + 1) + (xcd - r) * q) + off;
    const int MB = M / 128;
    const int sq = s >> 6, wi = s & 63;
    const int nsqm = MB >> 3;
    const int gm = sq % nsqm, gn = sq / nsqm;
    const int brow = (gm * 8 + (wi & 7)) * 128;
    const int bcol = (gn * 8 + (wi >> 3)) * 128;

    const int sr = tid >> 3;
    const int su = (tid & 7) ^ (sr & 7);
    const bf16* Ag = A + (size_t)(brow + sr) * K + su * 8;
    const bf16* Bg = B + (size_t)(bcol + sr) * K + su * 8;
    const size_t K64 = (size_t)64 * K;
    char* dst0 = lds + tid * 16;

    auto stage = [&](int bf, int kt) {
        char* d = dst0 + bf * 32768;
        gload_lds16(Ag + kt * 64, d);
        gload_lds16(Ag + K64 + kt * 64, d + 8192);
        gload_lds16(Bg + kt * 64, d + 16384);
        gload_lds16(Bg + K64 + kt * 64, d + 24576);
    };

    f32x4 acc[2][4] = {};
    const int NT = K >> 6;

    stage(0, 0);
    for (int kt = 0; kt < NT; ++kt) {
        const int cur = kt & 1;
        if (kt + 1 < NT) {
            stage(cur ^ 1, kt + 1);
            asm volatile("s_waitcnt vmcnt(4)" ::: "memory");
        } else {
            asm volatile("s_waitcnt vmcnt(0)" ::: "memory");
        }
        __builtin_amdgcn_s_barrier();

        const char* ab = lds + cur * 32768;
        const char* bb = ab + 16384;
        bf16x8 af[2][2], bfv[4][2];
        #pragma unroll
        for (int m = 0; m < 2; ++m) {
            const int rA = wr * 32 + m * 16 + lo;
            #pragma unroll
            for (int ks = 0; ks < 2; ++ks)
                af[m][ks] = *(const bf16x8*)(ab + rA * 128 + (((ks * 4 + hi) ^ (lo & 7)) << 4));
        }
        #pragma unroll
        for (int n = 0; n < 4; ++n) {
            const int rB = wc * 64 + n * 16 + lo;
            #pragma unroll
            for (int ks = 0; ks < 2; ++ks)
                bfv[n][ks] = *(const bf16x8*)(bb + rB * 128 + (((ks * 4 + hi) ^ (lo & 7)) << 4));
        }
        __builtin_amdgcn_s_setprio(1);
        #pragma unroll
        for (int m = 0; m < 2; ++m)
            #pragma unroll
            for (int n = 0; n < 4; ++n)
                #pragma unroll
                for (int ks = 0; ks < 2; ++ks)
                    acc[m][n] = __builtin_amdgcn_mfma_f32_16x16x32_bf16(af[m][ks], bfv[n][ks], acc[m][n], 0, 0, 0);
        __builtin_amdgcn_s_setprio(0);
        __builtin_amdgcn_s_barrier();
    }

    float* outF = (float*)OutP;
    bf16*  outB = (bf16*)OutP;
    #pragma unroll
    for (int n = 0; n < 4; ++n) {
        const int col = bcol + wc * 64 + n * 16 + lo;
        float bv = 0.f;
        if (EPI == 1 || EPI == 3) bv = bias[col];
        #pragma unroll
        for (int m = 0; m < 2; ++m) {
            #pragma unroll
            for (int rr = 0; rr < 4; ++rr) {
                const int row = brow + wr * 32 + m * 16 + hi * 4 + rr;
                float v = acc[m][n][rr];
                if (EPI == 0) {
                    outB[(size_t)row * N + col] = (bf16)v;
                } else if (EPI == 1) {
                    v += bv;
                    v = 0.5f * v * (1.0f + erff(v * 0.70710678118654752f));
                    outB[(size_t)row * N + col] = (bf16)v;
                } else if (EPI == 2) {
                    outF[(size_t)row * N + col] = res[(size_t)row * N + col] + v;
                } else {
                    outF[(size_t)row * N + col] = res[(size_t)row * N + col] + v + bv;
                }
            }
        }
    }
}

// ---------------------------------------------------------------- RoPE + GQA scatter (Q, K only; V handled by vtrans)
__global__ __launch_bounds__(256) void rope_scatter(const bf16* __restrict__ qkv,
                                                    const float* __restrict__ cosb,
                                                    const float* __restrict__ sinb,
                                                    bf16* __restrict__ Q,
                                                    bf16* __restrict__ Kg) {
    const int tid = threadIdx.x;
    const int row = blockIdx.x;          // b*T + t
    const int b = row >> 11, t = row & 2047;
    const bf16* src = qkv + (size_t)row * 3072;
    #pragma unroll
    for (int i = tid; i < 1280; i += 256) {
        int slot = i >> 6;               // 0..19 = g*5 + m  (m: 0-3 Q, 4 K)
        int d = i & 63;
        int g = slot / 5, m = slot - g * 5;
        int msrc = g * 6 + m;            // memory slot in qkv row
        float v1 = (float)src[msrc * 128 + d];
        float v2 = (float)src[msrc * 128 + d + 64];
        float c1 = cosb[t * 128 + d],      s1 = sinb[t * 128 + d];
        float c2 = cosb[t * 128 + d + 64], s2 = sinb[t * 128 + d + 64];
        float o1 = v1 * c1 - v2 * s1;
        float o2 = v2 * c2 + v1 * s2;
        if (m < 4) {
            int hh = g * 4 + m;
            size_t base = ((size_t)(b * 16 + hh) * 2048 + t) * 128;
            Q[base + d] = (bf16)o1;
            Q[base + d + 64] = (bf16)o2;
        } else {
            size_t base = ((size_t)(b * 4 + g) * 2048 + t) * 128;
            Kg[base + d] = (bf16)o1;
            Kg[base + d + 64] = (bf16)o2;
        }
    }
}

// ---------------------------------------------------------------- V transpose: qkvo -> Vt (B,4,128,T)
__global__ __launch_bounds__(256) void vtrans(const bf16* __restrict__ qkvo,
                                              bf16* __restrict__ Vt) {
    const int tid = threadIdx.x;
    const int t0 = blockIdx.x * 64;      // 32 t-tiles
    const int z  = blockIdx.y;           // b*4+g (8)
    const int b = z >> 2, g = z & 3;
    const int d = tid & 127;
    const int th = tid >> 7;             // t-half (0/1 -> 32 t each)
    const bf16* src = qkvo + (size_t)(b * 2048 + t0 + th * 32) * 3072 + g * 768 + 640 + d;
    bf16* dst = Vt + ((size_t)z * 128 + d) * 2048 + t0 + th * 32;
    #pragma unroll
    for (int c = 0; c < 4; ++c) {
        bf16x8 v;
        #pragma unroll
        for (int j = 0; j < 8; ++j)
            v[j] = src[(size_t)(c * 8 + j) * 3072];
        *(bf16x8*)(dst + c * 8) = v;
    }
}

// ---------------------------------------------------------------- causal flash attention
// Balanced pair {bx, 31-bx}; T14 async double-buffer staging; T13 defer-max;
// T5 setprio around MFMA clusters (attn waves are not barrier-lockstep: m191 +4-7%).
__global__ __launch_bounds__(256) void attn_kernel(const bf16* __restrict__ Q,
                                                   const bf16* __restrict__ Kg,
                                                   const bf16* __restrict__ Vt,
                                                   bf16* __restrict__ Y) {
    __shared__ __align__(16) bf16 Ks[2][64 * 128];
    __shared__ __align__(16) bf16 Vs[2][128 * 64];
    __shared__ __align__(16) bf16 Ps[4][16 * 80];

    const int tid = threadIdx.x;
    const int lane = tid & 63, w = tid >> 6;
    const int lo = lane & 15, hi = lane >> 4;
    const int bh = blockIdx.y;
    const int b = bh >> 4, h = bh & 15;
    const int g = h >> 2;

    const bf16* Kbase = Kg + (size_t)(b * 4 + g) * 2048 * 128;
    const bf16* Vbase = Vt + (size_t)(b * 4 + g) * 128 * 2048;
    const float scale = 0.08838834764831845f;
    bf16* pw = &Ps[w][0];

    bf16x8 kreg[4], vreg[4];

    #pragma unroll 1
    for (int pass = 0; pass < 2; ++pass) {
        const int qt = pass ? 31 - (int)blockIdx.x : (int)blockIdx.x;
        const int q0 = qt * 64;

        bf16x8 qf[4];
        {
            const size_t qbase = ((size_t)bh * 2048 + q0 + w * 16 + lo) * 128;
            #pragma unroll
            for (int dd = 0; dd < 4; ++dd)
                qf[dd] = *(const bf16x8*)(Q + qbase + dd * 32 + hi * 8);
        }

        float m_r[4], l_r[4];
        f32x4 oacc[8] = {};
        #pragma unroll
        for (int rr = 0; rr < 4; ++rr) { m_r[rr] = -1e30f; l_r[rr] = 0.f; }

        // ---- prologue: tile 0 -> buf 0
        #pragma unroll
        for (int it = 0; it < 4; ++it) {
            int ob = (it * 256 + tid) * 16;
            int rk = ob >> 8, cb = ob & 255;
            kreg[it] = *(const bf16x8*)(Kbase + (size_t)rk * 128 + (cb >> 1));
            int dv = ob >> 7, cv = ob & 127;
            vreg[it] = *(const bf16x8*)(Vbase + (size_t)dv * 2048 + (cv >> 1));
        }
        #pragma unroll
        for (int it = 0; it < 4; ++it) {
            int ob = (it * 256 + tid) * 16;
            int rk = ob >> 8, cb = ob & 255;
            *(bf16x8*)((char*)Ks[0] + rk * 256 + (cb ^ ((rk & 7) << 4))) = kreg[it];
            int dv = ob >> 7, cv = ob & 127;
            *(bf16x8*)((char*)Vs[0] + dv * 128 + (cv ^ ((dv & 7) << 4))) = vreg[it];
        }
        __syncthreads();
        int cur = 0;

        for (int kt = 0; kt <= qt; ++kt) {
            const bool pf = (kt < qt);
            // ---- issue next tile's global loads EARLY (latency hides under compute)
            if (pf) {
                #pragma unroll
                for (int it = 0; it < 4; ++it) {
                    int ob = (it * 256 + tid) * 16;
                    int rk = ob >> 8, cb = ob & 255;
                    kreg[it] = *(const bf16x8*)(Kbase + (size_t)((kt + 1) * 64 + rk) * 128 + (cb >> 1));
                    int dv = ob >> 7, cv = ob & 127;
                    vreg[it] = *(const bf16x8*)(Vbase + (size_t)dv * 2048 + (kt + 1) * 64 + (cv >> 1));
                }
            }

            const char* KsC = (const char*)Ks[cur];
            const char* VsC = (const char*)Vs[cur];

            // ---- S = Q K^T : 4 t-subtiles of 16
            f32x4 sj[4];
            __builtin_amdgcn_s_setprio(1);
            #pragma unroll
            for (int j = 0; j < 4; ++j) {
                f32x4 a = {};
                int rk = j * 16 + lo;
                #pragma unroll
                for (int dd = 0; dd < 4; ++dd) {
                    int cb = dd * 64 + hi * 16;
                    bf16x8 kf = *(const bf16x8*)(KsC + rk * 256 + (cb ^ ((rk & 7) << 4)));
                    a = __builtin_amdgcn_mfma_f32_16x16x32_bf16(qf[dd], kf, a, 0, 0, 0);
                }
                sj[j] = a;
            }
            __builtin_amdgcn_s_setprio(0);

            // ---- scale + causal mask
            float sv[4][4];
            const bool diag = (kt == qt);
            #pragma unroll
            for (int j = 0; j < 4; ++j)
                #pragma unroll
                for (int rr = 0; rr < 4; ++rr) {
                    float v = sj[j][rr] * scale;
                    if (diag) {
                        int tg = kt * 64 + j * 16 + lo;
                        int qg = q0 + w * 16 + hi * 4 + rr;
                        if (tg > qg) v = -1e30f;
                    }
                    sv[j][rr] = v;
                }

            // ---- tile max per row
            float mx[4];
            #pragma unroll
            for (int rr = 0; rr < 4; ++rr) {
                float m0 = fmaxf(fmaxf(sv[0][rr], sv[1][rr]), fmaxf(sv[2][rr], sv[3][rr]));
                #pragma unroll
                for (int off = 8; off; off >>= 1) m0 = fmaxf(m0, __shfl_xor(m0, off, 16));
                mx[rr] = m0;
            }

            // ---- defer-max: rescale only when max grew by > 8
            bool need = false;
            #pragma unroll
            for (int rr = 0; rr < 4; ++rr) need = need || (mx[rr] > m_r[rr] + 8.0f);
            if (__any(need)) {
                #pragma unroll
                for (int rr = 0; rr < 4; ++rr) {
                    float mnew = fmaxf(m_r[rr], mx[rr]);
                    float al = exp2f((m_r[rr] - mnew) * LOG2E);
                    l_r[rr] *= al;
                    m_r[rr] = mnew;
                    #pragma unroll
                    for (int dn = 0; dn < 8; ++dn) oacc[dn][rr] *= al;
                }
            }

            // ---- P = exp(S - m), row sums
            float p[4][4];
            #pragma unroll
            for (int rr = 0; rr < 4; ++rr) {
                #pragma unroll
                for (int j = 0; j < 4; ++j)
                    p[j][rr] = exp2f((sv[j][rr] - m_r[rr]) * LOG2E);
                float s0 = p[0][rr] + p[1][rr] + p[2][rr] + p[3][rr];
                #pragma unroll
                for (int off = 8; off; off >>= 1) s0 += __shfl_xor(s0, off, 16);
                l_r[rr] += s0;
            }

            // ---- write P to per-wave LDS [16 q][80 t]
            #pragma unroll
            for (int j = 0; j < 4; ++j)
                #pragma unroll
                for (int rr = 0; rr < 4; ++rr)
                    pw[(hi * 4 + rr) * 80 + j * 16 + lo] = (bf16)p[j][rr];

            // ---- O += P V
            __builtin_amdgcn_s_setprio(1);
            #pragma unroll
            for (int tc = 0; tc < 2; ++tc) {
                bf16x8 pf2 = *(const bf16x8*)(pw + lo * 80 + tc * 32 + hi * 8);
                #pragma unroll
                for (int dn = 0; dn < 8; ++dn) {
                    int rv = dn * 16 + lo;
                    int cv = tc * 64 + hi * 16;
                    bf16x8 vf = *(const bf16x8*)(VsC + rv * 128 + (cv ^ ((rv & 7) << 4)));
                    oacc[dn] = __builtin_amdgcn_mfma_f32_16x16x32_bf16(pf2, vf, oacc[dn], 0, 0, 0);
                }
            }
            __builtin_amdgcn_s_setprio(0);

            // ---- write next tile (regs -> other buffer), then single barrier
            if (pf) {
                #pragma unroll
                for (int it = 0; it < 4; ++it) {
                    int ob = (it * 256 + tid) * 16;
                    int rk = ob >> 8, cb = ob & 255;
                    *(bf16x8*)((char*)Ks[cur ^ 1] + rk * 256 + (cb ^ ((rk & 7) << 4))) = kreg[it];
                    int dv = ob >> 7, cv = ob & 127;
                    *(bf16x8*)((char*)Vs[cur ^ 1] + dv * 128 + (cv ^ ((dv & 7) << 4))) = vreg[it];
                }
            }
            __syncthreads();
            cur ^= 1;
        }

        // ---- epilogue: Y[(b, q, h*128 + d)] = O / l
        #pragma unroll
        for (int dn = 0; dn < 8; ++dn)
            #pragma unroll
            for (int rr = 0; rr < 4; ++rr) {
                int qg = q0 + w * 16 + hi * 4 + rr;
                Y[((size_t)b * 2048 + qg) * 2048 + h * 128 + dn * 16 + lo] =
                    (bf16)(oacc[dn][rr] / l_r[rr]);
            }
    }
}

// ---------------------------------------------------------------- launch
extern "C" void kernel_launch(void* const* d_in, const int* in_sizes, int n_in,
                              void* d_out, int out_size, void* d_ws, size_t ws_size,
                              hipStream_t stream) {
    const float* x      = (const float*)d_in[0];
    const float* cosb   = (const float*)d_in[1];
    const float* sinb   = (const float*)d_in[2];
    const float* ln1_w  = (const float*)d_in[4];
    const float* ln1_b  = (const float*)d_in[5];
    const float* qkv_w  = (const float*)d_in[6];
    const float* proj_w = (const float*)d_in[7];
    const float* ln2_w  = (const float*)d_in[8];
    const float* ln2_b  = (const float*)d_in[9];
    const float* fc1_w  = (const float*)d_in[10];
    const float* fc1_b  = (const float*)d_in[11];
    const float* fc2_w  = (const float*)d_in[12];
    const float* fc2_b  = (const float*)d_in[13];
    float* out = (float*)d_out;

    char* ws = (char*)d_ws;
    bf16*  w_qkv  = (bf16*)(ws + 0ull);            // 3072x2048
    bf16*  w_proj = (bf16*)(ws + 12582912ull);     // 2048x2048
    bf16*  w_fc1  = (bf16*)(ws + 20971520ull);     // 8192x2048
    bf16*  w_fc2  = (bf16*)(ws + 54525952ull);     // 2048x8192
    float* x2     = (float*)(ws + 88080384ull);    // 4096x2048 f32
    bf16*  lnout  = (bf16*)(ws + 121634816ull);    // 4096x2048
    char*  R      = ws + 138412032ull;             // aliased region (67.1 MB)
    bf16*  qkvo = (bf16*)(R);                      // 4096x3072
    bf16*  Qb   = (bf16*)(R + 25165824ull);        // 2,16,2048,128
    bf16*  Kb   = (bf16*)(R + 41943040ull);        // 2,4,2048,128
    bf16*  Vtb  = (bf16*)(R + 46137344ull);        // 2,4,128,2048
    bf16*  Yb   = (bf16*)(R + 50331648ull);        // 4096x2048
    bf16*  mlp  = (bf16*)(R);                      // 4096x8192 (aliases all above)

    cvt_bf16<<<6144,  256, 0, stream>>>(qkv_w,  w_qkv,  3072 * 2048);
    cvt_bf16<<<4096,  256, 0, stream>>>(proj_w, w_proj, 2048 * 2048);
    cvt_bf16<<<16384, 256, 0, stream>>>(fc1_w,  w_fc1,  8192 * 2048);
    cvt_bf16<<<16384, 256, 0, stream>>>(fc2_w,  w_fc2,  2048 * 8192);

    ln_kernel<<<4096, 256, 0, stream>>>(x, ln1_w, ln1_b, lnout);

    gemmB<0><<<768, 512, 0, stream>>>(lnout, w_qkv, qkvo, nullptr, nullptr,
                                      4096, 3072, 2048);

    rope_scatter<<<4096, 256, 0, stream>>>(qkvo, cosb, sinb, Qb, Kb);
    vtrans<<<dim3(32, 8), 256, 0, stream>>>(qkvo, Vtb);

    attn_kernel<<<dim3(16, 32), 256, 0, stream>>>(Qb, Kb, Vtb, Yb);

    gemmB<2><<<512, 512, 0, stream>>>(Yb, w_proj, x2, nullptr, x,
                                      4096, 2048, 2048);

    ln_kernel<<<4096, 256, 0, stream>>>(x2, ln2_w, ln2_b, lnout);

    gemmB<1><<<2048, 512, 0, stream>>>(lnout, w_fc1, mlp, fc1_b, nullptr,
                                       4096, 8192, 2048);

    gemmB<3><<<512, 512, 0, stream>>>(mlp, w_fc2, out, fc2_b, x2,
                                      4096, 2048, 8192);
}